// Round 11
// baseline (796.795 us; speedup 1.0000x reference)
//
#include <hip/hip_runtime.h>
#include <hip/hip_bf16.h>

#define NN 10000     // nodes
#define NE 100000    // edges
#define DD 64        // node_out_feats
#define EH_ 128      // edge_hidden_feats
#define NI_ 74       // node_in_feats
#define EI_ 12       // edge_in_feats
#define NSTEPS 6
#define PADN 10240
#define GCAP 16384   // max groups (ceil-sum bound 15625)
#define EPB 64       // edges per block in k_eh_s

typedef short bf16x8 __attribute__((ext_vector_type(8)));
typedef float f32x4 __attribute__((ext_vector_type(4)));

static __device__ __forceinline__ unsigned short f2b(float f) {
    unsigned int u = __float_as_uint(f);
    u += 0x7fffu + ((u >> 16) & 1u);
    return (unsigned short)(u >> 16);
}

__global__ void k_zero(float* p, int n) {
    int i = blockIdx.x * blockDim.x + threadIdx.x;
    if (i < n) p[i] = 0.f;
}

// node_feats = relu(x @ W_proj^T + b_proj); hidden = node_feats. One wave per node.
__global__ void k_proj(const float* __restrict__ x, const float* __restrict__ Wp,
                       const float* __restrict__ bp, float* __restrict__ nf,
                       float* __restrict__ hid) {
    int w = (blockIdx.x * blockDim.x + threadIdx.x) >> 6;
    int lane = threadIdx.x & 63;
    if (w >= NN) return;
    const float* xr = x + (size_t)w * NI_;
    float x0 = xr[lane];
    float x1 = (lane < NI_ - 64) ? xr[64 + lane] : 0.f;
    float acc = bp[lane];
    const float* wr = Wp + (size_t)lane * NI_;
    #pragma unroll
    for (int i = 0; i < 64; i++) acc += __shfl(x0, i, 64) * wr[i];
    #pragma unroll
    for (int i = 0; i < NI_ - 64; i++) acc += __shfl(x1, i, 64) * wr[64 + i];
    acc = fmaxf(acc, 0.f);
    nf[(size_t)w * DD + lane] = acc;
    hid[(size_t)w * DD + lane] = acc;
}

__global__ void k_hist(const int* __restrict__ srcv, int* __restrict__ hist) {
    int e = blockIdx.x * blockDim.x + threadIdx.x;
    if (e < NE) atomicAdd(&hist[srcv[e]], 1);
}

// exclusive scan of hist -> rowptr[0..NN], cursor copy. Single block 1024 thr.
__global__ void k_scan(const int* __restrict__ hist, int* __restrict__ rowptr,
                       int* __restrict__ cursor) {
    __shared__ int part[1024];
    int t = threadIdx.x;
    const int PER = (NN + 1023) / 1024;
    int b0 = t * PER;
    int sum = 0;
    for (int i = 0; i < PER; i++) { int b = b0 + i; if (b < NN) sum += hist[b]; }
    part[t] = sum;
    __syncthreads();
    for (int off = 1; off < 1024; off <<= 1) {
        int v = (t >= off) ? part[t - off] : 0;
        __syncthreads();
        part[t] += v;
        __syncthreads();
    }
    int run = (t > 0) ? part[t - 1] : 0;
    for (int i = 0; i <= PER; i++) {
        int b = b0 + i;
        if (b <= NN) {
            rowptr[b] = run;
            if (b < NN) cursor[b] = run;
        }
        if (b < NN && i < PER) run += hist[b];
        if (i == PER) break;
    }
}

__global__ void k_scatter(const int* __restrict__ srcv, const int* __restrict__ dstv,
                          int* __restrict__ cursor, int* __restrict__ perm,
                          int* __restrict__ dsts_s) {
    int e = blockIdx.x * blockDim.x + threadIdx.x;
    if (e >= NE) return;
    int s = srcv[e];
    int pos = atomicAdd(&cursor[s], 1);
    perm[pos] = e;
    dsts_s[pos] = dstv[e];
}

// Build group list: group = (src, base, cnt<=16) over src-sorted edge ranges.
__global__ void k_grp(const int* __restrict__ rowptr, int* __restrict__ g_src,
                      int* __restrict__ g_base, int* __restrict__ g_cnt,
                      int* __restrict__ d_ng) {
    __shared__ int part[1024];
    int t = threadIdx.x;
    const int PER = (NN + 1023) / 1024;
    int b0 = t * PER;
    int cg = 0;
    for (int i = 0; i < PER; i++) {
        int b = b0 + i;
        if (b < NN) { int d = rowptr[b + 1] - rowptr[b]; cg += (d + 15) >> 4; }
    }
    part[t] = cg;
    __syncthreads();
    for (int off = 1; off < 1024; off <<= 1) {
        int v = (t >= off) ? part[t - off] : 0;
        __syncthreads();
        part[t] += v;
        __syncthreads();
    }
    int run = (t > 0) ? part[t - 1] : 0;
    for (int i = 0; i < PER; i++) {
        int b = b0 + i;
        if (b >= NN) break;
        int r0 = rowptr[b], r1 = rowptr[b + 1];
        for (int p = r0; p < r1; p += 16) {
            g_src[run] = b;
            g_base[run] = p;
            int c = r1 - p; if (c > 16) c = 16;
            g_cnt[run] = c;
            run++;
        }
    }
    if (t == 1023) *d_ng = run;
}

// eh (sorted order, bf16) = relu(edge_attr[perm[p]] @ W_e1^T + b_e1).
// 64 edges per block; W1/b1/ea staged once in LDS; weight row in registers.
__global__ void k_eh_s(const float* __restrict__ ea, const float* __restrict__ W1,
                       const float* __restrict__ b1, const int* __restrict__ perm,
                       unsigned short* __restrict__ ehs) {
    __shared__ float s_W[EH_ * EI_];
    __shared__ float s_b[EH_];
    __shared__ float s_ea[EPB][EI_];
    __shared__ int s_perm[EPB];
    int t = threadIdx.x;
    int p0 = blockIdx.x * EPB;
    for (int i = t; i < EH_ * EI_; i += 256) s_W[i] = W1[i];
    if (t < EH_) s_b[t] = b1[t];
    if (t < EPB) s_perm[t] = (p0 + t < NE) ? perm[p0 + t] : 0;
    __syncthreads();
    for (int i = t; i < EPB * EI_; i += 256) {
        int pl = i / EI_, ii = i % EI_;
        s_ea[pl][ii] = (p0 + pl < NE) ? ea[(size_t)s_perm[pl] * EI_ + ii] : 0.f;
    }
    int le = t >> 7;       // 0..1
    int h = t & 127;
    float wrow[EI_];
    #pragma unroll
    for (int i = 0; i < EI_; i++) wrow[i] = s_W[h * EI_ + i];
    float bb = s_b[h];
    __syncthreads();
    for (int pl = le; pl < EPB; pl += 2) {
        int p = p0 + pl;
        if (p >= NE) break;
        float acc = bb;
        #pragma unroll
        for (int i = 0; i < EI_; i++) acc += s_ea[pl][i] * wrow[i];
        ehs[(size_t)p * EH_ + h] = f2b(fmaxf(acc, 0.f));
    }
}

// Pack W_e2 into bf16 MFMA A-fragment order for the fused kernel.
// Tile (ks,hB,f): idx = ((((ks*2+hB)*64+f)*2+frag)*4+g)*128 + n*8 + j,
// d=frag*32+g*8+j, h=ks*32+hB*16+n.
__global__ void k_pA(const float* __restrict__ W2, unsigned short* __restrict__ Apk) {
    int idx = blockIdx.x * 256 + threadIdx.x;
    if (idx >= (1 << 19)) return;
    int j = idx & 7;
    int n = (idx >> 3) & 15;
    int g = (idx >> 7) & 3;
    int frag = (idx >> 9) & 1;
    int f = (idx >> 10) & 63;
    int hB = (idx >> 16) & 1;
    int ks = idx >> 17;
    int d = frag * 32 + g * 8 + j;
    int h = ks * 32 + hB * 16 + n;
    Apk[idx] = f2b(W2[((size_t)(d * 64 + f)) * EH_ + h]);
}

__global__ void k_tG(const float* __restrict__ W, float* __restrict__ Wt) {
    int idx = blockIdx.x * 256 + threadIdx.x;
    if (idx >= 192 * 64) return;
    int j = idx / 64, d2 = idx % 64;
    Wt[d2 * 192 + j] = W[idx];
}

__global__ void k_tr64(const float* __restrict__ W, float* __restrict__ Wt) {
    int idx = blockIdx.x * 256 + threadIdx.x;
    if (idx >= 64 * 64) return;
    int r = idx >> 6, c = idx & 63;
    Wt[c * 64 + r] = W[idx];
}

__global__ void k_cnt(const int* __restrict__ dstv, float* __restrict__ cnt) {
    int e = blockIdx.x * blockDim.x + threadIdx.x;
    if (e < NE) atomicAdd(&cnt[dstv[e]], 1.0f);
}

// xp = nf @ W_lin^T + b_lin (-> bf16 xpb); btp = xp @ reshape(b_e2,64,64); agg = 0.
__global__ void k_xp(const float* __restrict__ nf, const float* __restrict__ WlT,
                     const float* __restrict__ bl, const float* __restrict__ be2,
                     unsigned short* __restrict__ xpb, float* __restrict__ btp,
                     float* __restrict__ agg) {
    int wid = (blockIdx.x * blockDim.x + threadIdx.x) >> 6;
    int lane = threadIdx.x & 63;
    int s0 = wid * 4;
    if (s0 >= NN) return;
    int nv = (NN - s0 < 4) ? (NN - s0) : 4;
    float nvv[4], acc[4], bt[4];
    float blv = bl[lane];
    #pragma unroll
    for (int i = 0; i < 4; i++) {
        int s = s0 + (i < nv ? i : nv - 1);
        nvv[i] = nf[(size_t)s * DD + lane];
        acc[i] = blv;
        bt[i] = 0.f;
    }
    for (int d = 0; d < 64; d++) {
        float wv = WlT[d * 64 + lane];
        #pragma unroll
        for (int i = 0; i < 4; i++)
            acc[i] = fmaf(__shfl(nvv[i], d, 64), wv, acc[i]);
    }
    for (int d = 0; d < 64; d++) {
        float bv = be2[d * 64 + lane];
        #pragma unroll
        for (int i = 0; i < 4; i++)
            bt[i] = fmaf(__shfl(acc[i], d, 64), bv, bt[i]);
    }
    #pragma unroll
    for (int i = 0; i < 4; i++) {
        if (i < nv) {
            xpb[(size_t)(s0 + i) * DD + lane] = f2b(acc[i]);
            btp[(size_t)(s0 + i) * DD + lane] = bt[i];
            agg[(size_t)(s0 + i) * DD + lane] = 0.f;
        }
    }
}

// Fused V-GEMM + edge MFMA. Block = 16 waves (1024 thr), 16 groups. (verified R9)
__global__ __launch_bounds__(1024, 8) void k_fv(
        const unsigned short* __restrict__ xpb,
        const unsigned short* __restrict__ Apk,
        const int* __restrict__ g_src, const int* __restrict__ g_base,
        const int* __restrict__ g_cnt, const int* __restrict__ d_ng,
        const unsigned short* __restrict__ ehs, const int* __restrict__ dsts,
        const float* __restrict__ btp, float* __restrict__ agg) {
    __shared__ unsigned char lds[65536];
    int ng = *d_ng;
    int nb = blockIdx.x * 16;
    if (nb >= ng) return;
    int tid = threadIdx.x;
    int w = tid >> 6, lane = tid & 63;      // w in [0,16)
    int g = lane >> 4, n = lane & 15;

    int srcn = g_src[nb + n];
    const unsigned short* xr = xpb + (size_t)srcn * DD + g * 8;
    bf16x8 xb0 = *(const bf16x8*)xr;
    bf16x8 xb1 = *(const bf16x8*)(xr + 32);

    int gi = nb + w;
    int sq = g_src[gi], bq = g_base[gi], cq = g_cnt[gi];

    f32x4 acc[4];
    #pragma unroll
    for (int nt = 0; nt < 4; nt++) {
        f32x4 z = {0.f, 0.f, 0.f, 0.f};
        acc[nt] = z;
    }

    for (int ks = 0; ks < 4; ks++) {
        if (ks) __syncthreads();
        #pragma unroll
        for (int hB = 0; hB < 2; hB++) {
            int ho = hB * 2 + (g >> 1);
            int hq0 = (g & 1) * 4;
            int abase = (n << 12) | (ho << 4) | (hq0 << 1);
            const unsigned short* apks =
                Apk + (size_t)((ks * 2 + hB) * 64 + (w << 2)) * 1024 + g * 128 + n * 8;
            #pragma unroll
            for (int fi = 0; fi < 4; fi++) {
                int f = (w << 2) + fi;
                const unsigned short* ap = apks + fi * 1024;
                bf16x8 A0 = *(const bf16x8*)ap;
                bf16x8 A1 = *(const bf16x8*)(ap + 512);
                f32x4 d = {0.f, 0.f, 0.f, 0.f};
                d = __builtin_amdgcn_mfma_f32_16x16x32_bf16(A0, xb0, d, 0, 0, 0);
                d = __builtin_amdgcn_mfma_f32_16x16x32_bf16(A1, xb1, d, 0, 0, 0);
                unsigned int lo = (unsigned)f2b(d[0]) | ((unsigned)f2b(d[1]) << 16);
                unsigned int hi = (unsigned)f2b(d[2]) | ((unsigned)f2b(d[3]) << 16);
                int addr = abase | (f << 6);
                addr ^= ((n ^ f) & 7) << 4;
                *(unsigned long long*)(lds + addr) =
                    (unsigned long long)lo | ((unsigned long long)hi << 32);
            }
        }
        bf16x8 aeh = *(const bf16x8*)(ehs + (size_t)(bq + n) * EH_ + ks * 32 + g * 8);
        __syncthreads();
        bf16x8 Bf[4];
        #pragma unroll
        for (int nt = 0; nt < 4; nt++) {
            int f = nt * 16 + n;
            int addr = (w << 12) | (f << 6) | (g << 4);
            addr ^= ((w ^ f) & 7) << 4;
            Bf[nt] = *(const bf16x8*)(lds + addr);
        }
        #pragma unroll
        for (int nt = 0; nt < 4; nt++)
            acc[nt] = __builtin_amdgcn_mfma_f32_16x16x32_bf16(aeh, Bf[nt], acc[nt], 0, 0, 0);
    }
    if (cq == 0) return;
    #pragma unroll
    for (int nt = 0; nt < 4; nt++) {
        float btv = btp[(size_t)sq * DD + nt * 16 + n];
        #pragma unroll
        for (int rg = 0; rg < 4; rg++) {
            int m = g * 4 + rg;
            if (m < cq) {
                int dn = dsts[bq + m];
                atomicAdd(&agg[(size_t)dn * DD + nt * 16 + n], acc[nt][rg] + btv);
            }
        }
    }
}

// Fused GRU + next-step xp. 16 waves/block (64 nodes), all weights LDS-staged.
__global__ __launch_bounds__(1024, 1) void k_gruxp(
        const float* __restrict__ agg, const float* __restrict__ cnt,
        const float* __restrict__ hid,
        const float* __restrict__ WihT, const float* __restrict__ WhhT,
        const float* __restrict__ bih, const float* __restrict__ bhh,
        const float* __restrict__ WlT, const float* __restrict__ bl,
        const float* __restrict__ be2,
        float* __restrict__ out_nf,
        unsigned short* __restrict__ xpb, float* __restrict__ btp,
        float* __restrict__ aggw, int doXp) {
    __shared__ float sWi[192 * 64];   // 48 KB, [d*192 + j]
    __shared__ float sWh[192 * 64];   // 48 KB
    __shared__ float sWl[64 * 64];    // 16 KB, [d*64 + lane]
    __shared__ float sBe[64 * 64];    // 16 KB
    int t = threadIdx.x;
    for (int i = t; i < 192 * 64; i += 1024) { sWi[i] = WihT[i]; sWh[i] = WhhT[i]; }
    for (int i = t; i < 64 * 64; i += 1024) { sWl[i] = WlT[i]; sBe[i] = be2[i]; }
    __syncthreads();
    int w = t >> 6, lane = t & 63;
    int wid = blockIdx.x * 16 + w;
    int s0 = wid * 4;
    if (s0 >= NN) return;
    int nv = (NN - s0 < 4) ? (NN - s0) : 4;
    float nfv[4], hv[4], gr[4], gz[4], gn[4], hr[4], hz[4], hn[4];
    float bi0 = bih[lane], bi1 = bih[64 + lane], bi2 = bih[128 + lane];
    float bh0 = bhh[lane], bh1 = bhh[64 + lane], bh2 = bhh[128 + lane];
    #pragma unroll
    for (int i = 0; i < 4; i++) {
        int s = s0 + (i < nv ? i : nv - 1);
        float c = fmaxf(cnt[s], 1.f);
        nfv[i] = fmaxf(agg[(size_t)s * DD + lane] / c, 0.f);
        hv[i] = hid[(size_t)s * DD + lane];
        gr[i] = bi0; gz[i] = bi1; gn[i] = bi2;
        hr[i] = bh0; hz[i] = bh1; hn[i] = bh2;
    }
    for (int d = 0; d < 64; d++) {
        const float* wi = sWi + d * 192;
        const float* wh = sWh + d * 192;
        float wi0 = wi[lane], wi1 = wi[64 + lane], wi2 = wi[128 + lane];
        float wh0 = wh[lane], wh1 = wh[64 + lane], wh2 = wh[128 + lane];
        #pragma unroll
        for (int i = 0; i < 4; i++) {
            float nd = __shfl(nfv[i], d, 64);
            float hd = __shfl(hv[i], d, 64);
            gr[i] = fmaf(nd, wi0, gr[i]);
            gz[i] = fmaf(nd, wi1, gz[i]);
            gn[i] = fmaf(nd, wi2, gn[i]);
            hr[i] = fmaf(hd, wh0, hr[i]);
            hz[i] = fmaf(hd, wh1, hz[i]);
            hn[i] = fmaf(hd, wh2, hn[i]);
        }
    }
    float newnf[4];
    #pragma unroll
    for (int i = 0; i < 4; i++) {
        float r = 1.f / (1.f + __expf(-(gr[i] + hr[i])));
        float z = 1.f / (1.f + __expf(-(gz[i] + hz[i])));
        float nn2 = tanhf(gn[i] + r * hn[i]);
        newnf[i] = (1.f - z) * nn2 + z * hv[i];
        if (i < nv) out_nf[(size_t)(s0 + i) * DD + lane] = newnf[i];
    }
    if (!doXp) return;
    float acc[4], bt[4];
    float blv = bl[lane];
    #pragma unroll
    for (int i = 0; i < 4; i++) { acc[i] = blv; bt[i] = 0.f; }
    for (int d = 0; d < 64; d++) {
        float wv = sWl[d * 64 + lane];
        #pragma unroll
        for (int i = 0; i < 4; i++)
            acc[i] = fmaf(__shfl(newnf[i], d, 64), wv, acc[i]);
    }
    for (int d = 0; d < 64; d++) {
        float bv = sBe[d * 64 + lane];
        #pragma unroll
        for (int i = 0; i < 4; i++)
            bt[i] = fmaf(__shfl(acc[i], d, 64), bv, bt[i]);
    }
    #pragma unroll
    for (int i = 0; i < 4; i++) {
        if (i < nv) {
            xpb[(size_t)(s0 + i) * DD + lane] = f2b(acc[i]);
            btp[(size_t)(s0 + i) * DD + lane] = bt[i];
            aggw[(size_t)(s0 + i) * DD + lane] = 0.f;
        }
    }
}

extern "C" void kernel_launch(void* const* d_in, const int* in_sizes, int n_in,
                              void* d_out, int out_size, void* d_ws, size_t ws_size,
                              hipStream_t stream) {
    const float* x   = (const float*)d_in[0];
    const int*   ei  = (const int*)d_in[1];
    const float* ea  = (const float*)d_in[2];
    const float* Wp  = (const float*)d_in[3];
    const float* bp  = (const float*)d_in[4];
    const float* W1  = (const float*)d_in[5];
    const float* b1  = (const float*)d_in[6];
    const float* W2  = (const float*)d_in[7];
    const float* b2  = (const float*)d_in[8];
    const float* Wl  = (const float*)d_in[9];
    const float* bl  = (const float*)d_in[10];
    const float* Wih = (const float*)d_in[11];
    const float* Whh = (const float*)d_in[12];
    const float* bih = (const float*)d_in[13];
    const float* bhh = (const float*)d_in[14];
    const int* srcv = ei;
    const int* dstv = ei + NE;

    float* p = (float*)d_ws;
    size_t off = 0;
    auto alloc = [&](size_t n) { n = (n + 3) & ~(size_t)3; float* q = p + off; off += n; return q; };
    float* nf   = alloc((size_t)NN * DD);
    float* hid  = alloc((size_t)NN * DD);
    float* btp  = alloc((size_t)NN * DD);
    float* agg  = alloc((size_t)NN * DD);
    float* cnt  = alloc(NN);
    unsigned short* ehs = (unsigned short*)alloc((size_t)(NE + 16) * EH_ / 2);  // bf16
    float* WihT = alloc(192 * 64);
    float* WhhT = alloc(192 * 64);
    float* WlT  = alloc(64 * 64);
    int* hist   = (int*)alloc(NN);
    int* rowptr = (int*)alloc(NN + 1);
    int* cursor = (int*)alloc(NN);
    int* perm   = (int*)alloc(NE);
    int* dsts_s = (int*)alloc(NE);
    int* g_src  = (int*)alloc(GCAP);
    int* g_base = (int*)alloc(GCAP);
    int* g_cnt  = (int*)alloc(GCAP);
    int* d_ng   = (int*)alloc(4);
    unsigned short* Apk = (unsigned short*)alloc((size_t)(1 << 19) / 2);       // bf16, 1MB
    unsigned short* xpb = (unsigned short*)alloc((size_t)PADN * DD / 2);       // bf16

    // ---- one-time preprocessing ----
    k_zero<<<(NN + 255) / 256, 256, 0, stream>>>(cnt, NN);
    k_zero<<<(NN + 255) / 256, 256, 0, stream>>>((float*)hist, NN);
    k_zero<<<(GCAP + 255) / 256, 256, 0, stream>>>((float*)g_src, GCAP);
    k_zero<<<(GCAP + 255) / 256, 256, 0, stream>>>((float*)g_base, GCAP);
    k_zero<<<(GCAP + 255) / 256, 256, 0, stream>>>((float*)g_cnt, GCAP);
    k_proj<<<(NN + 3) / 4, 256, 0, stream>>>(x, Wp, bp, nf, hid);
    k_pA<<<(1 << 19) / 256, 256, 0, stream>>>(W2, Apk);
    k_tG<<<48, 256, 0, stream>>>(Wih, WihT);
    k_tG<<<48, 256, 0, stream>>>(Whh, WhhT);
    k_tr64<<<16, 256, 0, stream>>>(Wl, WlT);
    k_cnt<<<(NE + 255) / 256, 256, 0, stream>>>(dstv, cnt);
    k_hist<<<(NE + 255) / 256, 256, 0, stream>>>(srcv, hist);
    k_scan<<<1, 1024, 0, stream>>>(hist, rowptr, cursor);
    k_scatter<<<(NE + 255) / 256, 256, 0, stream>>>(srcv, dstv, cursor, perm, dsts_s);
    k_eh_s<<<(NE + EPB - 1) / EPB, 256, 0, stream>>>(ea, W1, b1, perm, ehs);
    k_grp<<<1, 1024, 0, stream>>>(rowptr, g_src, g_base, g_cnt, d_ng);

    const int nw_quarter = (NN + 3) / 4;
    const int gru_blocks = (nw_quarter + 15) / 16;
    k_xp<<<(nw_quarter + 3) / 4, 256, 0, stream>>>(nf, WlT, bl, b2, xpb, btp, agg);
    for (int s = 0; s < NSTEPS; s++) {
        k_fv<<<GCAP / 16, 1024, 0, stream>>>(xpb, Apk, g_src, g_base, g_cnt, d_ng,
                                             ehs, dsts_s, btp, agg);
        float* dest = (s == NSTEPS - 1) ? (float*)d_out : nf;
        k_gruxp<<<gru_blocks, 1024, 0, stream>>>(agg, cnt, hid, WihT, WhhT,
                                                 bih, bhh, WlT, bl, b2,
                                                 dest, xpb, btp, agg,
                                                 (s < NSTEPS - 1) ? 1 : 0);
    }
}

// Round 12
// 785.454 us; speedup vs baseline: 1.0144x; 1.0144x over previous
//
#include <hip/hip_runtime.h>
#include <hip/hip_bf16.h>

#define NN 10000     // nodes
#define NE 100000    // edges
#define DD 64        // node_out_feats
#define EH_ 128      // edge_hidden_feats
#define NI_ 74       // node_in_feats
#define EI_ 12       // edge_in_feats
#define NSTEPS 6
#define PADN 10240
#define GCAP 16384   // max groups (ceil-sum bound 15625)
#define EPB 64       // edges per block in k_eh_s

typedef short bf16x8 __attribute__((ext_vector_type(8)));
typedef float f32x4 __attribute__((ext_vector_type(4)));

static __device__ __forceinline__ unsigned short f2b(float f) {
    unsigned int u = __float_as_uint(f);
    u += 0x7fffu + ((u >> 16) & 1u);
    return (unsigned short)(u >> 16);
}

__global__ void k_zero(float* p, int n) {
    int i = blockIdx.x * blockDim.x + threadIdx.x;
    if (i < n) p[i] = 0.f;
}

// node_feats = relu(x @ W_proj^T + b_proj); hidden = node_feats. One wave per node.
__global__ void k_proj(const float* __restrict__ x, const float* __restrict__ Wp,
                       const float* __restrict__ bp, float* __restrict__ nf,
                       float* __restrict__ hid) {
    int w = (blockIdx.x * blockDim.x + threadIdx.x) >> 6;
    int lane = threadIdx.x & 63;
    if (w >= NN) return;
    const float* xr = x + (size_t)w * NI_;
    float x0 = xr[lane];
    float x1 = (lane < NI_ - 64) ? xr[64 + lane] : 0.f;
    float acc = bp[lane];
    const float* wr = Wp + (size_t)lane * NI_;
    #pragma unroll
    for (int i = 0; i < 64; i++) acc += __shfl(x0, i, 64) * wr[i];
    #pragma unroll
    for (int i = 0; i < NI_ - 64; i++) acc += __shfl(x1, i, 64) * wr[64 + i];
    acc = fmaxf(acc, 0.f);
    nf[(size_t)w * DD + lane] = acc;
    hid[(size_t)w * DD + lane] = acc;
}

__global__ void k_hist(const int* __restrict__ srcv, int* __restrict__ hist) {
    int e = blockIdx.x * blockDim.x + threadIdx.x;
    if (e < NE) atomicAdd(&hist[srcv[e]], 1);
}

// exclusive scan of hist -> rowptr[0..NN], cursor copy. Single block 1024 thr.
__global__ void k_scan(const int* __restrict__ hist, int* __restrict__ rowptr,
                       int* __restrict__ cursor) {
    __shared__ int part[1024];
    int t = threadIdx.x;
    const int PER = (NN + 1023) / 1024;
    int b0 = t * PER;
    int sum = 0;
    for (int i = 0; i < PER; i++) { int b = b0 + i; if (b < NN) sum += hist[b]; }
    part[t] = sum;
    __syncthreads();
    for (int off = 1; off < 1024; off <<= 1) {
        int v = (t >= off) ? part[t - off] : 0;
        __syncthreads();
        part[t] += v;
        __syncthreads();
    }
    int run = (t > 0) ? part[t - 1] : 0;
    for (int i = 0; i <= PER; i++) {
        int b = b0 + i;
        if (b <= NN) {
            rowptr[b] = run;
            if (b < NN) cursor[b] = run;
        }
        if (b < NN && i < PER) run += hist[b];
        if (i == PER) break;
    }
}

__global__ void k_scatter(const int* __restrict__ srcv, const int* __restrict__ dstv,
                          int* __restrict__ cursor, int* __restrict__ perm,
                          int* __restrict__ dsts_s) {
    int e = blockIdx.x * blockDim.x + threadIdx.x;
    if (e >= NE) return;
    int s = srcv[e];
    int pos = atomicAdd(&cursor[s], 1);
    perm[pos] = e;
    dsts_s[pos] = dstv[e];
}

// Build group list: group = (src, base, cnt<=16) over src-sorted edge ranges.
__global__ void k_grp(const int* __restrict__ rowptr, int* __restrict__ g_src,
                      int* __restrict__ g_base, int* __restrict__ g_cnt,
                      int* __restrict__ d_ng) {
    __shared__ int part[1024];
    int t = threadIdx.x;
    const int PER = (NN + 1023) / 1024;
    int b0 = t * PER;
    int cg = 0;
    for (int i = 0; i < PER; i++) {
        int b = b0 + i;
        if (b < NN) { int d = rowptr[b + 1] - rowptr[b]; cg += (d + 15) >> 4; }
    }
    part[t] = cg;
    __syncthreads();
    for (int off = 1; off < 1024; off <<= 1) {
        int v = (t >= off) ? part[t - off] : 0;
        __syncthreads();
        part[t] += v;
        __syncthreads();
    }
    int run = (t > 0) ? part[t - 1] : 0;
    for (int i = 0; i < PER; i++) {
        int b = b0 + i;
        if (b >= NN) break;
        int r0 = rowptr[b], r1 = rowptr[b + 1];
        for (int p = r0; p < r1; p += 16) {
            g_src[run] = b;
            g_base[run] = p;
            int c = r1 - p; if (c > 16) c = 16;
            g_cnt[run] = c;
            run++;
        }
    }
    if (t == 1023) *d_ng = run;
}

// eh (sorted order, bf16) = relu(edge_attr[perm[p]] @ W_e1^T + b_e1).
// 64 edges per block; W1/b1/ea staged once in LDS; weight row in registers.
__global__ void k_eh_s(const float* __restrict__ ea, const float* __restrict__ W1,
                       const float* __restrict__ b1, const int* __restrict__ perm,
                       unsigned short* __restrict__ ehs) {
    __shared__ float s_W[EH_ * EI_];
    __shared__ float s_b[EH_];
    __shared__ float s_ea[EPB][EI_];
    __shared__ int s_perm[EPB];
    int t = threadIdx.x;
    int p0 = blockIdx.x * EPB;
    for (int i = t; i < EH_ * EI_; i += 256) s_W[i] = W1[i];
    if (t < EH_) s_b[t] = b1[t];
    if (t < EPB) s_perm[t] = (p0 + t < NE) ? perm[p0 + t] : 0;
    __syncthreads();
    for (int i = t; i < EPB * EI_; i += 256) {
        int pl = i / EI_, ii = i % EI_;
        s_ea[pl][ii] = (p0 + pl < NE) ? ea[(size_t)s_perm[pl] * EI_ + ii] : 0.f;
    }
    int le = t >> 7;       // 0..1
    int h = t & 127;
    float wrow[EI_];
    #pragma unroll
    for (int i = 0; i < EI_; i++) wrow[i] = s_W[h * EI_ + i];
    float bb = s_b[h];
    __syncthreads();
    for (int pl = le; pl < EPB; pl += 2) {
        int p = p0 + pl;
        if (p >= NE) break;
        float acc = bb;
        #pragma unroll
        for (int i = 0; i < EI_; i++) acc += s_ea[pl][i] * wrow[i];
        ehs[(size_t)p * EH_ + h] = f2b(fmaxf(acc, 0.f));
    }
}

// Pack W_e2 into bf16 MFMA A-fragment order for the fused kernel.
// Tile (ks,hB,f): idx = ((((ks*2+hB)*64+f)*2+frag)*4+g)*128 + n*8 + j,
// d=frag*32+g*8+j, h=ks*32+hB*16+n.
__global__ void k_pA(const float* __restrict__ W2, unsigned short* __restrict__ Apk) {
    int idx = blockIdx.x * 256 + threadIdx.x;
    if (idx >= (1 << 19)) return;
    int j = idx & 7;
    int n = (idx >> 3) & 15;
    int g = (idx >> 7) & 3;
    int frag = (idx >> 9) & 1;
    int f = (idx >> 10) & 63;
    int hB = (idx >> 16) & 1;
    int ks = idx >> 17;
    int d = frag * 32 + g * 8 + j;
    int h = ks * 32 + hB * 16 + n;
    Apk[idx] = f2b(W2[((size_t)(d * 64 + f)) * EH_ + h]);
}

__global__ void k_tG(const float* __restrict__ W, float* __restrict__ Wt) {
    int idx = blockIdx.x * 256 + threadIdx.x;
    if (idx >= 192 * 64) return;
    int j = idx / 64, d2 = idx % 64;
    Wt[d2 * 192 + j] = W[idx];
}

__global__ void k_tr64(const float* __restrict__ W, float* __restrict__ Wt) {
    int idx = blockIdx.x * 256 + threadIdx.x;
    if (idx >= 64 * 64) return;
    int r = idx >> 6, c = idx & 63;
    Wt[c * 64 + r] = W[idx];
}

__global__ void k_cnt(const int* __restrict__ dstv, float* __restrict__ cnt) {
    int e = blockIdx.x * blockDim.x + threadIdx.x;
    if (e < NE) atomicAdd(&cnt[dstv[e]], 1.0f);
}

// xp = nf @ W_lin^T + b_lin (-> bf16 xpb); btp = xp @ reshape(b_e2,64,64); agg = 0.
__global__ void k_xp(const float* __restrict__ nf, const float* __restrict__ WlT,
                     const float* __restrict__ bl, const float* __restrict__ be2,
                     unsigned short* __restrict__ xpb, float* __restrict__ btp,
                     float* __restrict__ agg) {
    int wid = (blockIdx.x * blockDim.x + threadIdx.x) >> 6;
    int lane = threadIdx.x & 63;
    int s0 = wid * 4;
    if (s0 >= NN) return;
    int nv = (NN - s0 < 4) ? (NN - s0) : 4;
    float nvv[4], acc[4], bt[4];
    float blv = bl[lane];
    #pragma unroll
    for (int i = 0; i < 4; i++) {
        int s = s0 + (i < nv ? i : nv - 1);
        nvv[i] = nf[(size_t)s * DD + lane];
        acc[i] = blv;
        bt[i] = 0.f;
    }
    for (int d = 0; d < 64; d++) {
        float wv = WlT[d * 64 + lane];
        #pragma unroll
        for (int i = 0; i < 4; i++)
            acc[i] = fmaf(__shfl(nvv[i], d, 64), wv, acc[i]);
    }
    for (int d = 0; d < 64; d++) {
        float bv = be2[d * 64 + lane];
        #pragma unroll
        for (int i = 0; i < 4; i++)
            bt[i] = fmaf(__shfl(acc[i], d, 64), bv, bt[i]);
    }
    #pragma unroll
    for (int i = 0; i < 4; i++) {
        if (i < nv) {
            xpb[(size_t)(s0 + i) * DD + lane] = f2b(acc[i]);
            btp[(size_t)(s0 + i) * DD + lane] = bt[i];
            agg[(size_t)(s0 + i) * DD + lane] = 0.f;
        }
    }
}

// Fused V-GEMM + edge MFMA. Block = 16 waves (1024 thr), 16 groups.
// Phase A now software-pipelined: 1-deep prefetch of A-fragment pairs over the
// 8 (hB,fi) iterations per ks to hide L2 latency within the 64-VGPR budget.
__global__ __launch_bounds__(1024, 8) void k_fv(
        const unsigned short* __restrict__ xpb,
        const unsigned short* __restrict__ Apk,
        const int* __restrict__ g_src, const int* __restrict__ g_base,
        const int* __restrict__ g_cnt, const int* __restrict__ d_ng,
        const unsigned short* __restrict__ ehs, const int* __restrict__ dsts,
        const float* __restrict__ btp, float* __restrict__ agg) {
    __shared__ unsigned char lds[65536];
    int ng = *d_ng;
    int nb = blockIdx.x * 16;
    if (nb >= ng) return;
    int tid = threadIdx.x;
    int w = tid >> 6, lane = tid & 63;      // w in [0,16)
    int g = lane >> 4, n = lane & 15;

    int srcn = g_src[nb + n];
    const unsigned short* xr = xpb + (size_t)srcn * DD + g * 8;
    bf16x8 xb0 = *(const bf16x8*)xr;
    bf16x8 xb1 = *(const bf16x8*)(xr + 32);

    int gi = nb + w;
    int sq = g_src[gi], bq = g_base[gi], cq = g_cnt[gi];

    f32x4 acc[4];
    #pragma unroll
    for (int nt = 0; nt < 4; nt++) {
        f32x4 z = {0.f, 0.f, 0.f, 0.f};
        acc[nt] = z;
    }

    for (int ks = 0; ks < 4; ks++) {
        if (ks) __syncthreads();
        // ---- phase A: V slice -> LDS, 8 pipelined iterations (it = hB*4+fi) ----
        const unsigned short* apbase =
            Apk + (size_t)(ks * 2) * 65536 + ((w << 2) << 10) + g * 128 + n * 8;
        bf16x8 cA0 = *(const bf16x8*)apbase;
        bf16x8 cA1 = *(const bf16x8*)(apbase + 512);
        #pragma unroll
        for (int it = 0; it < 8; it++) {
            bf16x8 nA0 = cA0, nA1 = cA1;
            if (it < 7) {
                const unsigned short* np =
                    apbase + (size_t)((it + 1) >> 2) * 65536 + (((it + 1) & 3) << 10);
                nA0 = *(const bf16x8*)np;
                nA1 = *(const bf16x8*)(np + 512);
            }
            f32x4 d = {0.f, 0.f, 0.f, 0.f};
            d = __builtin_amdgcn_mfma_f32_16x16x32_bf16(cA0, xb0, d, 0, 0, 0);
            d = __builtin_amdgcn_mfma_f32_16x16x32_bf16(cA1, xb1, d, 0, 0, 0);
            int hB = it >> 2, fi = it & 3;
            int ho = hB * 2 + (g >> 1);
            int hq0 = (g & 1) * 4;
            int abase = (n << 12) | (ho << 4) | (hq0 << 1);
            int f = (w << 2) + fi;
            unsigned int lo = (unsigned)f2b(d[0]) | ((unsigned)f2b(d[1]) << 16);
            unsigned int hi = (unsigned)f2b(d[2]) | ((unsigned)f2b(d[3]) << 16);
            int addr = abase | (f << 6);
            addr ^= ((n ^ f) & 7) << 4;
            *(unsigned long long*)(lds + addr) =
                (unsigned long long)lo | ((unsigned long long)hi << 32);
            cA0 = nA0; cA1 = nA1;
        }
        bf16x8 aeh = *(const bf16x8*)(ehs + (size_t)(bq + n) * EH_ + ks * 32 + g * 8);
        __syncthreads();
        // ---- phase B: edge MFMA from LDS (1 group per wave, sl = w) ----
        bf16x8 Bf[4];
        #pragma unroll
        for (int nt = 0; nt < 4; nt++) {
            int f = nt * 16 + n;
            int addr = (w << 12) | (f << 6) | (g << 4);
            addr ^= ((w ^ f) & 7) << 4;
            Bf[nt] = *(const bf16x8*)(lds + addr);
        }
        #pragma unroll
        for (int nt = 0; nt < 4; nt++)
            acc[nt] = __builtin_amdgcn_mfma_f32_16x16x32_bf16(aeh, Bf[nt], acc[nt], 0, 0, 0);
    }
    if (cq == 0) return;
    #pragma unroll
    for (int nt = 0; nt < 4; nt++) {
        float btv = btp[(size_t)sq * DD + nt * 16 + n];
        #pragma unroll
        for (int rg = 0; rg < 4; rg++) {
            int m = g * 4 + rg;
            if (m < cq) {
                int dn = dsts[bq + m];
                atomicAdd(&agg[(size_t)dn * DD + nt * 16 + n], acc[nt][rg] + btv);
            }
        }
    }
}

// Fused GRU + next-step xp. 8 nodes per wave (NN % 8 == 0), weights from L2.
__global__ void k_gruxp(const float* __restrict__ agg, const float* __restrict__ cnt,
                        const float* __restrict__ hid,
                        const float* __restrict__ WihT, const float* __restrict__ WhhT,
                        const float* __restrict__ bih, const float* __restrict__ bhh,
                        const float* __restrict__ WlT, const float* __restrict__ bl,
                        const float* __restrict__ be2,
                        float* __restrict__ out_nf,
                        unsigned short* __restrict__ xpb, float* __restrict__ btp,
                        float* __restrict__ aggw, int doXp) {
    int wid = (blockIdx.x * blockDim.x + threadIdx.x) >> 6;
    int lane = threadIdx.x & 63;
    int s0 = wid * 8;
    if (s0 >= NN) return;
    float nfv[8], hv[8], gr[8], gz[8], gn[8], hr[8], hz[8], hn[8];
    float bi0 = bih[lane], bi1 = bih[64 + lane], bi2 = bih[128 + lane];
    float bh0 = bhh[lane], bh1 = bhh[64 + lane], bh2 = bhh[128 + lane];
    #pragma unroll
    for (int i = 0; i < 8; i++) {
        int s = s0 + i;
        float c = fmaxf(cnt[s], 1.f);
        nfv[i] = fmaxf(agg[(size_t)s * DD + lane] / c, 0.f);
        hv[i] = hid[(size_t)s * DD + lane];
        gr[i] = bi0; gz[i] = bi1; gn[i] = bi2;
        hr[i] = bh0; hz[i] = bh1; hn[i] = bh2;
    }
    for (int d = 0; d < 64; d++) {
        const float* wi = WihT + d * 192;
        const float* wh = WhhT + d * 192;
        float wi0 = wi[lane], wi1 = wi[64 + lane], wi2 = wi[128 + lane];
        float wh0 = wh[lane], wh1 = wh[64 + lane], wh2 = wh[128 + lane];
        #pragma unroll
        for (int i = 0; i < 8; i++) {
            float nd = __shfl(nfv[i], d, 64);
            float hd = __shfl(hv[i], d, 64);
            gr[i] = fmaf(nd, wi0, gr[i]);
            gz[i] = fmaf(nd, wi1, gz[i]);
            gn[i] = fmaf(nd, wi2, gn[i]);
            hr[i] = fmaf(hd, wh0, hr[i]);
            hz[i] = fmaf(hd, wh1, hz[i]);
            hn[i] = fmaf(hd, wh2, hn[i]);
        }
    }
    float newnf[8];
    #pragma unroll
    for (int i = 0; i < 8; i++) {
        float r = 1.f / (1.f + __expf(-(gr[i] + hr[i])));
        float z = 1.f / (1.f + __expf(-(gz[i] + hz[i])));
        float nn2 = tanhf(gn[i] + r * hn[i]);
        newnf[i] = (1.f - z) * nn2 + z * hv[i];
        out_nf[(size_t)(s0 + i) * DD + lane] = newnf[i];
    }
    if (!doXp) return;
    float acc[8], bt[8];
    float blv = bl[lane];
    #pragma unroll
    for (int i = 0; i < 8; i++) { acc[i] = blv; bt[i] = 0.f; }
    for (int d = 0; d < 64; d++) {
        float wv = WlT[d * 64 + lane];
        #pragma unroll
        for (int i = 0; i < 8; i++)
            acc[i] = fmaf(__shfl(newnf[i], d, 64), wv, acc[i]);
    }
    for (int d = 0; d < 64; d++) {
        float bv = be2[d * 64 + lane];
        #pragma unroll
        for (int i = 0; i < 8; i++)
            bt[i] = fmaf(__shfl(acc[i], d, 64), bv, bt[i]);
    }
    #pragma unroll
    for (int i = 0; i < 8; i++) {
        xpb[(size_t)(s0 + i) * DD + lane] = f2b(acc[i]);
        btp[(size_t)(s0 + i) * DD + lane] = bt[i];
        aggw[(size_t)(s0 + i) * DD + lane] = 0.f;
    }
}

extern "C" void kernel_launch(void* const* d_in, const int* in_sizes, int n_in,
                              void* d_out, int out_size, void* d_ws, size_t ws_size,
                              hipStream_t stream) {
    const float* x   = (const float*)d_in[0];
    const int*   ei  = (const int*)d_in[1];
    const float* ea  = (const float*)d_in[2];
    const float* Wp  = (const float*)d_in[3];
    const float* bp  = (const float*)d_in[4];
    const float* W1  = (const float*)d_in[5];
    const float* b1  = (const float*)d_in[6];
    const float* W2  = (const float*)d_in[7];
    const float* b2  = (const float*)d_in[8];
    const float* Wl  = (const float*)d_in[9];
    const float* bl  = (const float*)d_in[10];
    const float* Wih = (const float*)d_in[11];
    const float* Whh = (const float*)d_in[12];
    const float* bih = (const float*)d_in[13];
    const float* bhh = (const float*)d_in[14];
    const int* srcv = ei;
    const int* dstv = ei + NE;

    float* p = (float*)d_ws;
    size_t off = 0;
    auto alloc = [&](size_t n) { n = (n + 3) & ~(size_t)3; float* q = p + off; off += n; return q; };
    float* nf   = alloc((size_t)NN * DD);
    float* hid  = alloc((size_t)NN * DD);
    float* btp  = alloc((size_t)NN * DD);
    float* agg  = alloc((size_t)NN * DD);
    float* cnt  = alloc(NN);
    unsigned short* ehs = (unsigned short*)alloc((size_t)(NE + 16) * EH_ / 2);  // bf16
    float* WihT = alloc(192 * 64);
    float* WhhT = alloc(192 * 64);
    float* WlT  = alloc(64 * 64);
    int* hist   = (int*)alloc(NN);
    int* rowptr = (int*)alloc(NN + 1);
    int* cursor = (int*)alloc(NN);
    int* perm   = (int*)alloc(NE);
    int* dsts_s = (int*)alloc(NE);
    int* g_src  = (int*)alloc(GCAP);
    int* g_base = (int*)alloc(GCAP);
    int* g_cnt  = (int*)alloc(GCAP);
    int* d_ng   = (int*)alloc(4);
    unsigned short* Apk = (unsigned short*)alloc((size_t)(1 << 19) / 2);       // bf16, 1MB
    unsigned short* xpb = (unsigned short*)alloc((size_t)PADN * DD / 2);       // bf16

    // ---- one-time preprocessing ----
    k_zero<<<(NN + 255) / 256, 256, 0, stream>>>(cnt, NN);
    k_zero<<<(NN + 255) / 256, 256, 0, stream>>>((float*)hist, NN);
    k_zero<<<(GCAP + 255) / 256, 256, 0, stream>>>((float*)g_src, GCAP);
    k_zero<<<(GCAP + 255) / 256, 256, 0, stream>>>((float*)g_base, GCAP);
    k_zero<<<(GCAP + 255) / 256, 256, 0, stream>>>((float*)g_cnt, GCAP);
    k_proj<<<(NN + 3) / 4, 256, 0, stream>>>(x, Wp, bp, nf, hid);
    k_pA<<<(1 << 19) / 256, 256, 0, stream>>>(W2, Apk);
    k_tG<<<48, 256, 0, stream>>>(Wih, WihT);
    k_tG<<<48, 256, 0, stream>>>(Whh, WhhT);
    k_tr64<<<16, 256, 0, stream>>>(Wl, WlT);
    k_cnt<<<(NE + 255) / 256, 256, 0, stream>>>(dstv, cnt);
    k_hist<<<(NE + 255) / 256, 256, 0, stream>>>(srcv, hist);
    k_scan<<<1, 1024, 0, stream>>>(hist, rowptr, cursor);
    k_scatter<<<(NE + 255) / 256, 256, 0, stream>>>(srcv, dstv, cursor, perm, dsts_s);
    k_eh_s<<<(NE + EPB - 1) / EPB, 256, 0, stream>>>(ea, W1, b1, perm, ehs);
    k_grp<<<1, 1024, 0, stream>>>(rowptr, g_src, g_base, g_cnt, d_ng);

    const int nw_quarter = (NN + 3) / 4;
    const int nw_eighth = (NN + 7) / 8;
    k_xp<<<(nw_quarter + 3) / 4, 256, 0, stream>>>(nf, WlT, bl, b2, xpb, btp, agg);
    for (int s = 0; s < NSTEPS; s++) {
        k_fv<<<GCAP / 16, 1024, 0, stream>>>(xpb, Apk, g_src, g_base, g_cnt, d_ng,
                                             ehs, dsts_s, btp, agg);
        float* dest = (s == NSTEPS - 1) ? (float*)d_out : nf;
        k_gruxp<<<(nw_eighth + 3) / 4, 256, 0, stream>>>(agg, cnt, hid, WihT, WhhT,
                                                         bih, bhh, WlT, bl, b2,
                                                         dest, xpb, btp, agg,
                                                         (s < NSTEPS - 1) ? 1 : 0);
    }
}

// Round 13
// 568.244 us; speedup vs baseline: 1.4022x; 1.3822x over previous
//
#include <hip/hip_runtime.h>
#include <hip/hip_bf16.h>

#define NN 10000     // nodes
#define NE 100000    // edges
#define DD 64        // node_out_feats
#define EH_ 128      // edge_hidden_feats
#define NI_ 74       // node_in_feats
#define EI_ 12       // edge_in_feats
#define NSTEPS 6
#define PADN 10240
#define GCAP 16384   // max groups (ceil-sum bound 15625)
#define EPB 64       // edges per block in k_eh_s

// Gpk region offsets (ushort elements)
#define RZ_OFF 0          // 8 ct x 4 q
#define NI_OFF 16384      // 4 ct x 2 q
#define NH_OFF 20480
#define WL_OFF 24576
#define BE_OFF 28672
#define G_TOT  32768

typedef short bf16x8 __attribute__((ext_vector_type(8)));
typedef float f32x4 __attribute__((ext_vector_type(4)));

static __device__ __forceinline__ unsigned short f2b(float f) {
    unsigned int u = __float_as_uint(f);
    u += 0x7fffu + ((u >> 16) & 1u);
    return (unsigned short)(u >> 16);
}

__global__ void k_zero(float* p, int n) {
    int i = blockIdx.x * blockDim.x + threadIdx.x;
    if (i < n) p[i] = 0.f;
}

// node_feats = relu(x @ W_proj^T + b_proj); hidden = node_feats. One wave per node.
__global__ void k_proj(const float* __restrict__ x, const float* __restrict__ Wp,
                       const float* __restrict__ bp, float* __restrict__ nf,
                       float* __restrict__ hid) {
    int w = (blockIdx.x * blockDim.x + threadIdx.x) >> 6;
    int lane = threadIdx.x & 63;
    if (w >= NN) return;
    const float* xr = x + (size_t)w * NI_;
    float x0 = xr[lane];
    float x1 = (lane < NI_ - 64) ? xr[64 + lane] : 0.f;
    float acc = bp[lane];
    const float* wr = Wp + (size_t)lane * NI_;
    #pragma unroll
    for (int i = 0; i < 64; i++) acc += __shfl(x0, i, 64) * wr[i];
    #pragma unroll
    for (int i = 0; i < NI_ - 64; i++) acc += __shfl(x1, i, 64) * wr[64 + i];
    acc = fmaxf(acc, 0.f);
    nf[(size_t)w * DD + lane] = acc;
    hid[(size_t)w * DD + lane] = acc;
}

__global__ void k_hist(const int* __restrict__ srcv, int* __restrict__ hist) {
    int e = blockIdx.x * blockDim.x + threadIdx.x;
    if (e < NE) atomicAdd(&hist[srcv[e]], 1);
}

// exclusive scan of hist -> rowptr[0..NN], cursor copy. Single block 1024 thr.
__global__ void k_scan(const int* __restrict__ hist, int* __restrict__ rowptr,
                       int* __restrict__ cursor) {
    __shared__ int part[1024];
    int t = threadIdx.x;
    const int PER = (NN + 1023) / 1024;
    int b0 = t * PER;
    int sum = 0;
    for (int i = 0; i < PER; i++) { int b = b0 + i; if (b < NN) sum += hist[b]; }
    part[t] = sum;
    __syncthreads();
    for (int off = 1; off < 1024; off <<= 1) {
        int v = (t >= off) ? part[t - off] : 0;
        __syncthreads();
        part[t] += v;
        __syncthreads();
    }
    int run = (t > 0) ? part[t - 1] : 0;
    for (int i = 0; i <= PER; i++) {
        int b = b0 + i;
        if (b <= NN) {
            rowptr[b] = run;
            if (b < NN) cursor[b] = run;
        }
        if (b < NN && i < PER) run += hist[b];
        if (i == PER) break;
    }
}

__global__ void k_scatter(const int* __restrict__ srcv, const int* __restrict__ dstv,
                          int* __restrict__ cursor, int* __restrict__ perm,
                          int* __restrict__ dsts_s) {
    int e = blockIdx.x * blockDim.x + threadIdx.x;
    if (e >= NE) return;
    int s = srcv[e];
    int pos = atomicAdd(&cursor[s], 1);
    perm[pos] = e;
    dsts_s[pos] = dstv[e];
}

// Build group list: group = (src, base, cnt<=16) over src-sorted edge ranges.
__global__ void k_grp(const int* __restrict__ rowptr, int* __restrict__ g_src,
                      int* __restrict__ g_base, int* __restrict__ g_cnt,
                      int* __restrict__ d_ng) {
    __shared__ int part[1024];
    int t = threadIdx.x;
    const int PER = (NN + 1023) / 1024;
    int b0 = t * PER;
    int cg = 0;
    for (int i = 0; i < PER; i++) {
        int b = b0 + i;
        if (b < NN) { int d = rowptr[b + 1] - rowptr[b]; cg += (d + 15) >> 4; }
    }
    part[t] = cg;
    __syncthreads();
    for (int off = 1; off < 1024; off <<= 1) {
        int v = (t >= off) ? part[t - off] : 0;
        __syncthreads();
        part[t] += v;
        __syncthreads();
    }
    int run = (t > 0) ? part[t - 1] : 0;
    for (int i = 0; i < PER; i++) {
        int b = b0 + i;
        if (b >= NN) break;
        int r0 = rowptr[b], r1 = rowptr[b + 1];
        for (int p = r0; p < r1; p += 16) {
            g_src[run] = b;
            g_base[run] = p;
            int c = r1 - p; if (c > 16) c = 16;
            g_cnt[run] = c;
            run++;
        }
    }
    if (t == 1023) *d_ng = run;
}

// eh (sorted order, bf16) = relu(edge_attr[perm[p]] @ W_e1^T + b_e1). 64 edges/block.
__global__ void k_eh_s(const float* __restrict__ ea, const float* __restrict__ W1,
                       const float* __restrict__ b1, const int* __restrict__ perm,
                       unsigned short* __restrict__ ehs) {
    __shared__ float s_W[EH_ * EI_];
    __shared__ float s_b[EH_];
    __shared__ float s_ea[EPB][EI_];
    __shared__ int s_perm[EPB];
    int t = threadIdx.x;
    int p0 = blockIdx.x * EPB;
    for (int i = t; i < EH_ * EI_; i += 256) s_W[i] = W1[i];
    if (t < EH_) s_b[t] = b1[t];
    if (t < EPB) s_perm[t] = (p0 + t < NE) ? perm[p0 + t] : 0;
    __syncthreads();
    for (int i = t; i < EPB * EI_; i += 256) {
        int pl = i / EI_, ii = i % EI_;
        s_ea[pl][ii] = (p0 + pl < NE) ? ea[(size_t)s_perm[pl] * EI_ + ii] : 0.f;
    }
    int le = t >> 7;
    int h = t & 127;
    float wrow[EI_];
    #pragma unroll
    for (int i = 0; i < EI_; i++) wrow[i] = s_W[h * EI_ + i];
    float bb = s_b[h];
    __syncthreads();
    for (int pl = le; pl < EPB; pl += 2) {
        int p = p0 + pl;
        if (p >= NE) break;
        float acc = bb;
        #pragma unroll
        for (int i = 0; i < EI_; i++) acc += s_ea[pl][i] * wrow[i];
        ehs[(size_t)p * EH_ + h] = f2b(fmaxf(acc, 0.f));
    }
}

// Pack W_e2 into bf16 MFMA A-fragment order for k_fv (verified R9).
__global__ void k_pA(const float* __restrict__ W2, unsigned short* __restrict__ Apk) {
    int idx = blockIdx.x * 256 + threadIdx.x;
    if (idx >= (1 << 19)) return;
    int j = idx & 7;
    int n = (idx >> 3) & 15;
    int g = (idx >> 7) & 3;
    int frag = (idx >> 9) & 1;
    int f = (idx >> 10) & 63;
    int hB = (idx >> 16) & 1;
    int ks = idx >> 17;
    int d = frag * 32 + g * 8 + j;
    int h = ks * 32 + hB * 16 + n;
    Apk[idx] = f2b(W2[((size_t)(d * 64 + f)) * EH_ + h]);
}

// Pack GRU/xp weights into MFMA B-fragment order.
// Region layout: OFF + ((ct*nq+q)*4+g)*128 + n*8 + j ; element B[k=q*32+g*8+j][c=ct*16+n].
__global__ void k_pG(const float* __restrict__ Wih, const float* __restrict__ Whh,
                     const float* __restrict__ Wl, const float* __restrict__ be2,
                     unsigned short* __restrict__ Gpk) {
    int idx = blockIdx.x * 256 + threadIdx.x;
    if (idx >= G_TOT) return;
    int j = idx & 7, n = (idx >> 3) & 15, g = (idx >> 7) & 3;
    float v;
    if (idx < NI_OFF) {                       // rz: nq=4, K=128, c in [0,128)
        int rem = idx >> 9;
        int q = rem & 3, ct = rem >> 2;
        int c = ct * 16 + n, k = q * 32 + g * 8 + j;
        v = (k < 64) ? Wih[(size_t)c * 64 + k] : Whh[(size_t)c * 64 + (k - 64)];
    } else if (idx < NH_OFF) {                // i_n: nq=2
        int l = idx - NI_OFF; int rem = l >> 9;
        int q = rem & 1, ct = rem >> 1;
        int c = ct * 16 + n, k = q * 32 + g * 8 + j;
        v = Wih[(size_t)(128 + c) * 64 + k];
    } else if (idx < WL_OFF) {                // h_n
        int l = idx - NH_OFF; int rem = l >> 9;
        int q = rem & 1, ct = rem >> 1;
        int c = ct * 16 + n, k = q * 32 + g * 8 + j;
        v = Whh[(size_t)(128 + c) * 64 + k];
    } else if (idx < BE_OFF) {                // Wl
        int l = idx - WL_OFF; int rem = l >> 9;
        int q = rem & 1, ct = rem >> 1;
        int c = ct * 16 + n, k = q * 32 + g * 8 + j;
        v = Wl[(size_t)c * 64 + k];
    } else {                                  // be2 reshaped [d][f]
        int l = idx - BE_OFF; int rem = l >> 9;
        int q = rem & 1, ct = rem >> 1;
        int c = ct * 16 + n, k = q * 32 + g * 8 + j;
        v = be2[(size_t)k * 64 + c];
    }
    Gpk[idx] = f2b(v);
}

__global__ void k_tr64(const float* __restrict__ W, float* __restrict__ Wt) {
    int idx = blockIdx.x * 256 + threadIdx.x;
    if (idx >= 64 * 64) return;
    int r = idx >> 6, c = idx & 63;
    Wt[c * 64 + r] = W[idx];
}

__global__ void k_cnt(const int* __restrict__ dstv, float* __restrict__ cnt) {
    int e = blockIdx.x * blockDim.x + threadIdx.x;
    if (e < NE) atomicAdd(&cnt[dstv[e]], 1.0f);
}

// bf16 pack of hid (once): pad rows zero.
__global__ void k_hb(const float* __restrict__ hid, unsigned short* __restrict__ hidb) {
    int i = blockIdx.x * 256 + threadIdx.x;
    if (i >= PADN * DD) return;
    int node = i >> 6;
    hidb[i] = (node < NN) ? f2b(hid[i]) : 0;
}

// per-step: nfvb = bf16(relu(agg/cnt)); agg = 0.
__global__ void k_prep(const float* __restrict__ agg, const float* __restrict__ cnt,
                       unsigned short* __restrict__ nfvb, float* __restrict__ aggw) {
    int i = blockIdx.x * 256 + threadIdx.x;
    if (i >= PADN * DD) return;
    int node = i >> 6;
    if (node >= NN) { nfvb[i] = 0; return; }
    float c = fmaxf(cnt[node], 1.f);
    nfvb[i] = f2b(fmaxf(agg[i] / c, 0.f));
    aggw[i] = 0.f;
}

// Initial xp = nf @ Wl^T + bl (-> xpb); btp = xp @ be2; agg = 0. VALU, once.
__global__ void k_xp(const float* __restrict__ nf, const float* __restrict__ WlT,
                     const float* __restrict__ bl, const float* __restrict__ be2,
                     unsigned short* __restrict__ xpb, float* __restrict__ btp,
                     float* __restrict__ agg) {
    int wid = (blockIdx.x * blockDim.x + threadIdx.x) >> 6;
    int lane = threadIdx.x & 63;
    int s0 = wid * 4;
    if (s0 >= NN) return;
    int nv = (NN - s0 < 4) ? (NN - s0) : 4;
    float nvv[4], acc[4], bt[4];
    float blv = bl[lane];
    #pragma unroll
    for (int i = 0; i < 4; i++) {
        int s = s0 + (i < nv ? i : nv - 1);
        nvv[i] = nf[(size_t)s * DD + lane];
        acc[i] = blv;
        bt[i] = 0.f;
    }
    for (int d = 0; d < 64; d++) {
        float wv = WlT[d * 64 + lane];
        #pragma unroll
        for (int i = 0; i < 4; i++)
            acc[i] = fmaf(__shfl(nvv[i], d, 64), wv, acc[i]);
    }
    for (int d = 0; d < 64; d++) {
        float bv = be2[d * 64 + lane];
        #pragma unroll
        for (int i = 0; i < 4; i++)
            bt[i] = fmaf(__shfl(acc[i], d, 64), bv, bt[i]);
    }
    #pragma unroll
    for (int i = 0; i < 4; i++) {
        if (i < nv) {
            xpb[(size_t)(s0 + i) * DD + lane] = f2b(acc[i]);
            btp[(size_t)(s0 + i) * DD + lane] = bt[i];
            agg[(size_t)(s0 + i) * DD + lane] = 0.f;
        }
    }
}

// Fused V-GEMM + edge MFMA. Block = 16 waves (1024 thr), 16 groups. (verified R9)
__global__ __launch_bounds__(1024, 8) void k_fv(
        const unsigned short* __restrict__ xpb,
        const unsigned short* __restrict__ Apk,
        const int* __restrict__ g_src, const int* __restrict__ g_base,
        const int* __restrict__ g_cnt, const int* __restrict__ d_ng,
        const unsigned short* __restrict__ ehs, const int* __restrict__ dsts,
        const float* __restrict__ btp, float* __restrict__ agg) {
    __shared__ unsigned char lds[65536];
    int ng = *d_ng;
    int nb = blockIdx.x * 16;
    if (nb >= ng) return;
    int tid = threadIdx.x;
    int w = tid >> 6, lane = tid & 63;
    int g = lane >> 4, n = lane & 15;

    int srcn = g_src[nb + n];
    const unsigned short* xr = xpb + (size_t)srcn * DD + g * 8;
    bf16x8 xb0 = *(const bf16x8*)xr;
    bf16x8 xb1 = *(const bf16x8*)(xr + 32);

    int gi = nb + w;
    int sq = g_src[gi], bq = g_base[gi], cq = g_cnt[gi];

    f32x4 acc[4];
    #pragma unroll
    for (int nt = 0; nt < 4; nt++) {
        f32x4 z = {0.f, 0.f, 0.f, 0.f};
        acc[nt] = z;
    }

    for (int ks = 0; ks < 4; ks++) {
        if (ks) __syncthreads();
        #pragma unroll
        for (int hB = 0; hB < 2; hB++) {
            int ho = hB * 2 + (g >> 1);
            int hq0 = (g & 1) * 4;
            int abase = (n << 12) | (ho << 4) | (hq0 << 1);
            const unsigned short* apks =
                Apk + (size_t)((ks * 2 + hB) * 64 + (w << 2)) * 1024 + g * 128 + n * 8;
            #pragma unroll
            for (int fi = 0; fi < 4; fi++) {
                int f = (w << 2) + fi;
                const unsigned short* ap = apks + fi * 1024;
                bf16x8 A0 = *(const bf16x8*)ap;
                bf16x8 A1 = *(const bf16x8*)(ap + 512);
                f32x4 d = {0.f, 0.f, 0.f, 0.f};
                d = __builtin_amdgcn_mfma_f32_16x16x32_bf16(A0, xb0, d, 0, 0, 0);
                d = __builtin_amdgcn_mfma_f32_16x16x32_bf16(A1, xb1, d, 0, 0, 0);
                unsigned int lo = (unsigned)f2b(d[0]) | ((unsigned)f2b(d[1]) << 16);
                unsigned int hi = (unsigned)f2b(d[2]) | ((unsigned)f2b(d[3]) << 16);
                int addr = abase | (f << 6);
                addr ^= ((n ^ f) & 7) << 4;
                *(unsigned long long*)(lds + addr) =
                    (unsigned long long)lo | ((unsigned long long)hi << 32);
            }
        }
        bf16x8 aeh = *(const bf16x8*)(ehs + (size_t)(bq + n) * EH_ + ks * 32 + g * 8);
        __syncthreads();
        bf16x8 Bf[4];
        #pragma unroll
        for (int nt = 0; nt < 4; nt++) {
            int f = nt * 16 + n;
            int addr = (w << 12) | (f << 6) | (g << 4);
            addr ^= ((w ^ f) & 7) << 4;
            Bf[nt] = *(const bf16x8*)(lds + addr);
        }
        #pragma unroll
        for (int nt = 0; nt < 4; nt++)
            acc[nt] = __builtin_amdgcn_mfma_f32_16x16x32_bf16(aeh, Bf[nt], acc[nt], 0, 0, 0);
    }
    if (cq == 0) return;
    #pragma unroll
    for (int nt = 0; nt < 4; nt++) {
        float btv = btp[(size_t)sq * DD + nt * 16 + n];
        #pragma unroll
        for (int rg = 0; rg < 4; rg++) {
            int m = g * 4 + rg;
            if (m < cq) {
                int dn = dsts[bq + m];
                atomicAdd(&agg[(size_t)dn * DD + nt * 16 + n], acc[nt][rg] + btv);
            }
        }
    }
}

// MFMA GRU + xp + btp. Block = 4 waves, 64 nodes (4 m-tiles of 16).
// Wave w owns gate cols j = w*16+n. rz via K=128 GEMM over [nfv|hid].
__global__ void k_gx(const unsigned short* __restrict__ nfvb,
                     const unsigned short* __restrict__ hidb,
                     const float* __restrict__ hid,
                     const unsigned short* __restrict__ Gpk,
                     const float* __restrict__ bih, const float* __restrict__ bhh,
                     const float* __restrict__ bl,
                     float* __restrict__ out_nf, unsigned short* __restrict__ xpb,
                     float* __restrict__ btp, int doXp) {
    __shared__ unsigned short s_nf[64 * 64];
    __shared__ unsigned short s_xp[64 * 64];
    int tid = threadIdx.x;
    int w = tid >> 6, lane = tid & 63;
    int g = lane >> 4, n = lane & 15;
    int nb = blockIdx.x * 64;
    int jj = w * 16 + n;

    // B-fragments (register-resident)
    bf16x8 Br[4], Bz[4], Bi[2], Bh[2], Bw[2], Be[2];
    #pragma unroll
    for (int q = 0; q < 4; q++) {
        Br[q] = *(const bf16x8*)(Gpk + RZ_OFF + (size_t)(((w) * 4 + q) * 4 + g) * 128 + n * 8);
        Bz[q] = *(const bf16x8*)(Gpk + RZ_OFF + (size_t)(((w + 4) * 4 + q) * 4 + g) * 128 + n * 8);
    }
    #pragma unroll
    for (int q = 0; q < 2; q++) {
        Bi[q] = *(const bf16x8*)(Gpk + NI_OFF + (size_t)((w * 2 + q) * 4 + g) * 128 + n * 8);
        Bh[q] = *(const bf16x8*)(Gpk + NH_OFF + (size_t)((w * 2 + q) * 4 + g) * 128 + n * 8);
        Bw[q] = *(const bf16x8*)(Gpk + WL_OFF + (size_t)((w * 2 + q) * 4 + g) * 128 + n * 8);
        Be[q] = *(const bf16x8*)(Gpk + BE_OFF + (size_t)((w * 2 + q) * 4 + g) * 128 + n * 8);
    }
    float br_ = bih[jj] + bhh[jj];
    float bz_ = bih[64 + jj] + bhh[64 + jj];
    float bi_ = bih[128 + jj];
    float bh_ = bhh[128 + jj];
    float blv = bl[jj];

    #pragma unroll
    for (int mt = 0; mt < 4; mt++) {
        int arow = nb + mt * 16 + n;
        const unsigned short* na = nfvb + (size_t)arow * DD + g * 8;
        const unsigned short* ha = hidb + (size_t)arow * DD + g * 8;
        bf16x8 A0 = *(const bf16x8*)na, A1 = *(const bf16x8*)(na + 32);
        bf16x8 H0 = *(const bf16x8*)ha, H1 = *(const bf16x8*)(ha + 32);
        f32x4 aR = {0.f, 0.f, 0.f, 0.f}, aZ = aR, aI = aR, aH = aR;
        aR = __builtin_amdgcn_mfma_f32_16x16x32_bf16(A0, Br[0], aR, 0, 0, 0);
        aR = __builtin_amdgcn_mfma_f32_16x16x32_bf16(A1, Br[1], aR, 0, 0, 0);
        aR = __builtin_amdgcn_mfma_f32_16x16x32_bf16(H0, Br[2], aR, 0, 0, 0);
        aR = __builtin_amdgcn_mfma_f32_16x16x32_bf16(H1, Br[3], aR, 0, 0, 0);
        aZ = __builtin_amdgcn_mfma_f32_16x16x32_bf16(A0, Bz[0], aZ, 0, 0, 0);
        aZ = __builtin_amdgcn_mfma_f32_16x16x32_bf16(A1, Bz[1], aZ, 0, 0, 0);
        aZ = __builtin_amdgcn_mfma_f32_16x16x32_bf16(H0, Bz[2], aZ, 0, 0, 0);
        aZ = __builtin_amdgcn_mfma_f32_16x16x32_bf16(H1, Bz[3], aZ, 0, 0, 0);
        aI = __builtin_amdgcn_mfma_f32_16x16x32_bf16(A0, Bi[0], aI, 0, 0, 0);
        aI = __builtin_amdgcn_mfma_f32_16x16x32_bf16(A1, Bi[1], aI, 0, 0, 0);
        aH = __builtin_amdgcn_mfma_f32_16x16x32_bf16(H0, Bh[0], aH, 0, 0, 0);
        aH = __builtin_amdgcn_mfma_f32_16x16x32_bf16(H1, Bh[1], aH, 0, 0, 0);
        #pragma unroll
        for (int rg = 0; rg < 4; rg++) {
            int row = mt * 16 + g * 4 + rg;
            int node = nb + row;
            float r = 1.f / (1.f + __expf(-(aR[rg] + br_)));
            float z = 1.f / (1.f + __expf(-(aZ[rg] + bz_)));
            float nn2 = tanhf(aI[rg] + bi_ + r * (aH[rg] + bh_));
            float hv = (node < NN) ? hid[(size_t)node * DD + jj] : 0.f;
            float nf_ = (1.f - z) * nn2 + z * hv;
            if (node < NN) out_nf[(size_t)node * DD + jj] = nf_;
            int ba = (row * 128 + jj * 2) ^ ((row & 7) << 4);
            s_nf[ba >> 1] = f2b(nf_);
        }
    }
    if (!doXp) return;
    __syncthreads();
    // xp = newnf @ Wl^T + bl
    #pragma unroll
    for (int mt = 0; mt < 4; mt++) {
        int row = mt * 16 + n;
        int sw = (row & 7) << 4;
        bf16x8 X0 = *(const bf16x8*)((const unsigned char*)s_nf + ((row * 128 + g * 16) ^ sw));
        bf16x8 X1 = *(const bf16x8*)((const unsigned char*)s_nf + ((row * 128 + 64 + g * 16) ^ sw));
        f32x4 aX = {0.f, 0.f, 0.f, 0.f};
        aX = __builtin_amdgcn_mfma_f32_16x16x32_bf16(X0, Bw[0], aX, 0, 0, 0);
        aX = __builtin_amdgcn_mfma_f32_16x16x32_bf16(X1, Bw[1], aX, 0, 0, 0);
        #pragma unroll
        for (int rg = 0; rg < 4; rg++) {
            int row2 = mt * 16 + g * 4 + rg;
            int ba = (row2 * 128 + jj * 2) ^ ((row2 & 7) << 4);
            s_xp[ba >> 1] = f2b(aX[rg] + blv);
        }
    }
    __syncthreads();
    // xpb global (row-major bf16), coalesced from LDS
    {
        int row = w * 16 + n;
        int sw = (row & 7) << 4;
        #pragma unroll
        for (int h2 = 0; h2 < 2; h2++) {
            int byteo = (row * 128 + (h2 * 4 + g) * 16) ^ sw;
            bf16x8 v = *(const bf16x8*)((const unsigned char*)s_xp + byteo);
            *(bf16x8*)(xpb + (size_t)(nb + row) * DD + (h2 * 4 + g) * 8) = v;
        }
    }
    // btp = xp @ be2
    #pragma unroll
    for (int mt = 0; mt < 4; mt++) {
        int row = mt * 16 + n;
        int sw = (row & 7) << 4;
        bf16x8 X0 = *(const bf16x8*)((const unsigned char*)s_xp + ((row * 128 + g * 16) ^ sw));
        bf16x8 X1 = *(const bf16x8*)((const unsigned char*)s_xp + ((row * 128 + 64 + g * 16) ^ sw));
        f32x4 aB = {0.f, 0.f, 0.f, 0.f};
        aB = __builtin_amdgcn_mfma_f32_16x16x32_bf16(X0, Be[0], aB, 0, 0, 0);
        aB = __builtin_amdgcn_mfma_f32_16x16x32_bf16(X1, Be[1], aB, 0, 0, 0);
        #pragma unroll
        for (int rg = 0; rg < 4; rg++) {
            int node = nb + mt * 16 + g * 4 + rg;
            if (node < NN) btp[(size_t)node * DD + jj] = aB[rg];
        }
    }
}

extern "C" void kernel_launch(void* const* d_in, const int* in_sizes, int n_in,
                              void* d_out, int out_size, void* d_ws, size_t ws_size,
                              hipStream_t stream) {
    const float* x   = (const float*)d_in[0];
    const int*   ei  = (const int*)d_in[1];
    const float* ea  = (const float*)d_in[2];
    const float* Wp  = (const float*)d_in[3];
    const float* bp  = (const float*)d_in[4];
    const float* W1  = (const float*)d_in[5];
    const float* b1  = (const float*)d_in[6];
    const float* W2  = (const float*)d_in[7];
    const float* b2  = (const float*)d_in[8];
    const float* Wl  = (const float*)d_in[9];
    const float* bl  = (const float*)d_in[10];
    const float* Wih = (const float*)d_in[11];
    const float* Whh = (const float*)d_in[12];
    const float* bih = (const float*)d_in[13];
    const float* bhh = (const float*)d_in[14];
    const int* srcv = ei;
    const int* dstv = ei + NE;

    float* p = (float*)d_ws;
    size_t off = 0;
    auto alloc = [&](size_t n) { n = (n + 3) & ~(size_t)3; float* q = p + off; off += n; return q; };
    float* nf   = alloc((size_t)NN * DD);
    float* hid  = alloc((size_t)NN * DD);
    float* btp  = alloc((size_t)NN * DD);
    float* agg  = alloc((size_t)NN * DD);
    float* cnt  = alloc(NN);
    unsigned short* ehs = (unsigned short*)alloc((size_t)(NE + 16) * EH_ / 2);  // bf16
    float* WlT  = alloc(64 * 64);
    int* hist   = (int*)alloc(NN);
    int* rowptr = (int*)alloc(NN + 1);
    int* cursor = (int*)alloc(NN);
    int* perm   = (int*)alloc(NE);
    int* dsts_s = (int*)alloc(NE);
    int* g_src  = (int*)alloc(GCAP);
    int* g_base = (int*)alloc(GCAP);
    int* g_cnt  = (int*)alloc(GCAP);
    int* d_ng   = (int*)alloc(4);
    unsigned short* Apk  = (unsigned short*)alloc((size_t)(1 << 19) / 2);      // bf16, 1MB
    unsigned short* Gpk  = (unsigned short*)alloc((size_t)G_TOT / 2);          // bf16, 64KB
    unsigned short* xpb  = (unsigned short*)alloc((size_t)PADN * DD / 2);      // bf16
    unsigned short* nfvb = (unsigned short*)alloc((size_t)PADN * DD / 2);      // bf16
    unsigned short* hidb = (unsigned short*)alloc((size_t)PADN * DD / 2);      // bf16

    // ---- one-time preprocessing ----
    k_zero<<<(NN + 255) / 256, 256, 0, stream>>>(cnt, NN);
    k_zero<<<(NN + 255) / 256, 256, 0, stream>>>((float*)hist, NN);
    k_zero<<<(GCAP + 255) / 256, 256, 0, stream>>>((float*)g_src, GCAP);
    k_zero<<<(GCAP + 255) / 256, 256, 0, stream>>>((float*)g_base, GCAP);
    k_zero<<<(GCAP + 255) / 256, 256, 0, stream>>>((float*)g_cnt, GCAP);
    k_proj<<<(NN + 3) / 4, 256, 0, stream>>>(x, Wp, bp, nf, hid);
    k_pA<<<(1 << 19) / 256, 256, 0, stream>>>(W2, Apk);
    k_pG<<<(G_TOT + 255) / 256, 256, 0, stream>>>(Wih, Whh, Wl, b2, Gpk);
    k_tr64<<<16, 256, 0, stream>>>(Wl, WlT);
    k_hb<<<(PADN * DD + 255) / 256, 256, 0, stream>>>(hid, hidb);
    k_cnt<<<(NE + 255) / 256, 256, 0, stream>>>(dstv, cnt);
    k_hist<<<(NE + 255) / 256, 256, 0, stream>>>(srcv, hist);
    k_scan<<<1, 1024, 0, stream>>>(hist, rowptr, cursor);
    k_scatter<<<(NE + 255) / 256, 256, 0, stream>>>(srcv, dstv, cursor, perm, dsts_s);
    k_eh_s<<<(NE + EPB - 1) / EPB, 256, 0, stream>>>(ea, W1, b1, perm, ehs);
    k_grp<<<1, 1024, 0, stream>>>(rowptr, g_src, g_base, g_cnt, d_ng);

    const int nw_quarter = (NN + 3) / 4;
    const int gx_blocks = (NN + 63) / 64;
    k_xp<<<(nw_quarter + 3) / 4, 256, 0, stream>>>(nf, WlT, bl, b2, xpb, btp, agg);
    for (int s = 0; s < NSTEPS; s++) {
        k_fv<<<GCAP / 16, 1024, 0, stream>>>(xpb, Apk, g_src, g_base, g_cnt, d_ng,
                                             ehs, dsts_s, btp, agg);
        k_prep<<<(PADN * DD + 255) / 256, 256, 0, stream>>>(agg, cnt, nfvb, agg);
        float* dest = (s == NSTEPS - 1) ? (float*)d_out : nf;
        k_gx<<<gx_blocks, 256, 0, stream>>>(nfvb, hidb, hid, Gpk, bih, bhh, bl,
                                            dest, xpb, btp,
                                            (s < NSTEPS - 1) ? 1 : 0);
    }
}

// Round 15
// 555.029 us; speedup vs baseline: 1.4356x; 1.0238x over previous
//
#include <hip/hip_runtime.h>
#include <hip/hip_bf16.h>

#define NN 10000     // nodes
#define NE 100000    // edges
#define DD 64        // node_out_feats
#define EH_ 128      // edge_hidden_feats
#define NI_ 74       // node_in_feats
#define EI_ 12       // edge_in_feats
#define NSTEPS 6
#define PADN 10240
#define GCAP 16384   // max groups (ceil-sum bound 15625)
#define EPB 64       // edges per block in k_eh_s

// Gpk region offsets (ushort elements)
#define RZ_OFF 0          // 8 ct x 4 q
#define NI_OFF 16384      // 4 ct x 2 q
#define NH_OFF 20480
#define WL_OFF 24576
#define BE_OFF 28672
#define G_TOT  32768

typedef short bf16x8 __attribute__((ext_vector_type(8)));
typedef float f32x4 __attribute__((ext_vector_type(4)));

static __device__ __forceinline__ unsigned short f2b(float f) {
    unsigned int u = __float_as_uint(f);
    u += 0x7fffu + ((u >> 16) & 1u);
    return (unsigned short)(u >> 16);
}

__global__ void k_zero(float* p, int n) {
    int i = blockIdx.x * blockDim.x + threadIdx.x;
    if (i < n) p[i] = 0.f;
}

__global__ void k_zero2(float* a, float* b, int n) {
    int i = blockIdx.x * blockDim.x + threadIdx.x;
    if (i < n) { a[i] = 0.f; b[i] = 0.f; }
}

// node_feats = relu(x @ W_proj^T + b_proj); hidden = node_feats; hidb = bf16(hid).
// One wave per node; PADN waves total, pad waves zero hidb only.
__global__ void k_proj(const float* __restrict__ x, const float* __restrict__ Wp,
                       const float* __restrict__ bp, float* __restrict__ nf,
                       float* __restrict__ hid, unsigned short* __restrict__ hidb) {
    int w = (blockIdx.x * blockDim.x + threadIdx.x) >> 6;
    int lane = threadIdx.x & 63;
    if (w >= PADN) return;
    if (w >= NN) { hidb[(size_t)w * DD + lane] = 0; return; }
    const float* xr = x + (size_t)w * NI_;
    float x0 = xr[lane];
    float x1 = (lane < NI_ - 64) ? xr[64 + lane] : 0.f;
    float acc = bp[lane];
    const float* wr = Wp + (size_t)lane * NI_;
    #pragma unroll
    for (int i = 0; i < 64; i++) acc += __shfl(x0, i, 64) * wr[i];
    #pragma unroll
    for (int i = 0; i < NI_ - 64; i++) acc += __shfl(x1, i, 64) * wr[64 + i];
    acc = fmaxf(acc, 0.f);
    nf[(size_t)w * DD + lane] = acc;
    hid[(size_t)w * DD + lane] = acc;
    hidb[(size_t)w * DD + lane] = f2b(acc);
}

// merged degree kernels: hist[src]++ (int), cnt[dst]++ (float)
__global__ void k_degs(const int* __restrict__ srcv, const int* __restrict__ dstv,
                       int* __restrict__ hist, float* __restrict__ cnt) {
    int e = blockIdx.x * blockDim.x + threadIdx.x;
    if (e < NE) {
        atomicAdd(&hist[srcv[e]], 1);
        atomicAdd(&cnt[dstv[e]], 1.0f);
    }
}

// merged: exclusive scan of hist -> rowptr/cursor, then group-list build.
// Single block 1024 thr. Phase-2 group counts derive from hist (no dependence
// on phase-1 rowptr writes except through the barrier-ordered reads).
__global__ void k_scangrp(const int* __restrict__ hist, int* __restrict__ rowptr,
                          int* __restrict__ cursor, int* __restrict__ g_src,
                          int* __restrict__ g_base, int* __restrict__ g_cnt,
                          int* __restrict__ d_ng) {
    __shared__ int part[1024];
    int t = threadIdx.x;
    const int PER = (NN + 1023) / 1024;
    int b0 = t * PER;
    // ---- phase 1: edge-count scan -> rowptr, cursor ----
    int sum = 0;
    for (int i = 0; i < PER; i++) { int b = b0 + i; if (b < NN) sum += hist[b]; }
    part[t] = sum;
    __syncthreads();
    for (int off = 1; off < 1024; off <<= 1) {
        int v = (t >= off) ? part[t - off] : 0;
        __syncthreads();
        part[t] += v;
        __syncthreads();
    }
    int run = (t > 0) ? part[t - 1] : 0;
    for (int i = 0; i <= PER; i++) {
        int b = b0 + i;
        if (b <= NN) {
            rowptr[b] = run;
            if (b < NN) cursor[b] = run;
        }
        if (b < NN && i < PER) run += hist[b];
        if (i == PER) break;
    }
    __syncthreads();   // rowptr visible block-wide; part[] reads of phase 1 done
    // ---- phase 2: group-count scan + emit ----
    int cg = 0;
    for (int i = 0; i < PER; i++) {
        int b = b0 + i;
        if (b < NN) cg += (hist[b] + 15) >> 4;
    }
    part[t] = cg;
    __syncthreads();
    for (int off = 1; off < 1024; off <<= 1) {
        int v = (t >= off) ? part[t - off] : 0;
        __syncthreads();
        part[t] += v;
        __syncthreads();
    }
    int grun = (t > 0) ? part[t - 1] : 0;
    for (int i = 0; i < PER; i++) {
        int b = b0 + i;
        if (b >= NN) break;
        int r0 = rowptr[b], r1 = rowptr[b + 1];
        for (int p = r0; p < r1; p += 16) {
            g_src[grun] = b;
            g_base[grun] = p;
            int c = r1 - p; if (c > 16) c = 16;
            g_cnt[grun] = c;
            grun++;
        }
    }
    if (t == 1023) *d_ng = grun;
}

__global__ void k_scatter(const int* __restrict__ srcv, const int* __restrict__ dstv,
                          int* __restrict__ cursor, int* __restrict__ perm,
                          int* __restrict__ dsts_s) {
    int e = blockIdx.x * blockDim.x + threadIdx.x;
    if (e >= NE) return;
    int s = srcv[e];
    int pos = atomicAdd(&cursor[s], 1);
    perm[pos] = e;
    dsts_s[pos] = dstv[e];
}

// eh (sorted order, bf16) = relu(edge_attr[perm[p]] @ W_e1^T + b_e1). 64 edges/block.
__global__ void k_eh_s(const float* __restrict__ ea, const float* __restrict__ W1,
                       const float* __restrict__ b1, const int* __restrict__ perm,
                       unsigned short* __restrict__ ehs) {
    __shared__ float s_W[EH_ * EI_];
    __shared__ float s_b[EH_];
    __shared__ float s_ea[EPB][EI_];
    __shared__ int s_perm[EPB];
    int t = threadIdx.x;
    int p0 = blockIdx.x * EPB;
    for (int i = t; i < EH_ * EI_; i += 256) s_W[i] = W1[i];
    if (t < EH_) s_b[t] = b1[t];
    if (t < EPB) s_perm[t] = (p0 + t < NE) ? perm[p0 + t] : 0;
    __syncthreads();
    for (int i = t; i < EPB * EI_; i += 256) {
        int pl = i / EI_, ii = i % EI_;
        s_ea[pl][ii] = (p0 + pl < NE) ? ea[(size_t)s_perm[pl] * EI_ + ii] : 0.f;
    }
    int le = t >> 7;
    int h = t & 127;
    float wrow[EI_];
    #pragma unroll
    for (int i = 0; i < EI_; i++) wrow[i] = s_W[h * EI_ + i];
    float bb = s_b[h];
    __syncthreads();
    for (int pl = le; pl < EPB; pl += 2) {
        int p = p0 + pl;
        if (p >= NE) break;
        float acc = bb;
        #pragma unroll
        for (int i = 0; i < EI_; i++) acc += s_ea[pl][i] * wrow[i];
        ehs[(size_t)p * EH_ + h] = f2b(fmaxf(acc, 0.f));
    }
}

// Pack W_e2 into bf16 MFMA A-fragment order for k_fv (verified R9).
__global__ void k_pA(const float* __restrict__ W2, unsigned short* __restrict__ Apk) {
    int idx = blockIdx.x * 256 + threadIdx.x;
    if (idx >= (1 << 19)) return;
    int j = idx & 7;
    int n = (idx >> 3) & 15;
    int g = (idx >> 7) & 3;
    int frag = (idx >> 9) & 1;
    int f = (idx >> 10) & 63;
    int hB = (idx >> 16) & 1;
    int ks = idx >> 17;
    int d = frag * 32 + g * 8 + j;
    int h = ks * 32 + hB * 16 + n;
    Apk[idx] = f2b(W2[((size_t)(d * 64 + f)) * EH_ + h]);
}

// Pack GRU/xp weights into MFMA B-fragment order.
__global__ void k_pG(const float* __restrict__ Wih, const float* __restrict__ Whh,
                     const float* __restrict__ Wl, const float* __restrict__ be2,
                     unsigned short* __restrict__ Gpk) {
    int idx = blockIdx.x * 256 + threadIdx.x;
    if (idx >= G_TOT) return;
    int j = idx & 7, n = (idx >> 3) & 15, g = (idx >> 7) & 3;
    float v;
    if (idx < NI_OFF) {                       // rz: nq=4, K=128, c in [0,128)
        int rem = idx >> 9;
        int q = rem & 3, ct = rem >> 2;
        int c = ct * 16 + n, k = q * 32 + g * 8 + j;
        v = (k < 64) ? Wih[(size_t)c * 64 + k] : Whh[(size_t)c * 64 + (k - 64)];
    } else if (idx < NH_OFF) {                // i_n: nq=2
        int l = idx - NI_OFF; int rem = l >> 9;
        int q = rem & 1, ct = rem >> 1;
        int c = ct * 16 + n, k = q * 32 + g * 8 + j;
        v = Wih[(size_t)(128 + c) * 64 + k];
    } else if (idx < WL_OFF) {                // h_n
        int l = idx - NH_OFF; int rem = l >> 9;
        int q = rem & 1, ct = rem >> 1;
        int c = ct * 16 + n, k = q * 32 + g * 8 + j;
        v = Whh[(size_t)(128 + c) * 64 + k];
    } else if (idx < BE_OFF) {                // Wl
        int l = idx - WL_OFF; int rem = l >> 9;
        int q = rem & 1, ct = rem >> 1;
        int c = ct * 16 + n, k = q * 32 + g * 8 + j;
        v = Wl[(size_t)c * 64 + k];
    } else {                                  // be2 reshaped [d][f]
        int l = idx - BE_OFF; int rem = l >> 9;
        int q = rem & 1, ct = rem >> 1;
        int c = ct * 16 + n, k = q * 32 + g * 8 + j;
        v = be2[(size_t)k * 64 + c];
    }
    Gpk[idx] = f2b(v);
}

__global__ void k_tr64(const float* __restrict__ W, float* __restrict__ Wt) {
    int idx = blockIdx.x * 256 + threadIdx.x;
    if (idx >= 64 * 64) return;
    int r = idx >> 6, c = idx & 63;
    Wt[c * 64 + r] = W[idx];
}

// per-step: nfvb = bf16(relu(agg/cnt)); agg = 0. (aggw NOT restrict: aliases agg)
__global__ void k_prep(const float* __restrict__ agg, const float* __restrict__ cnt,
                       unsigned short* __restrict__ nfvb, float* aggw) {
    int i = blockIdx.x * 256 + threadIdx.x;
    if (i >= PADN * DD) return;
    int node = i >> 6;
    if (node >= NN) { nfvb[i] = 0; return; }
    float c = fmaxf(cnt[node], 1.f);
    nfvb[i] = f2b(fmaxf(agg[i] / c, 0.f));
    aggw[i] = 0.f;
}

// Initial xp = nf @ Wl^T + bl (-> xpb); btp = xp @ be2; agg = 0. VALU, once.
__global__ void k_xp(const float* __restrict__ nf, const float* __restrict__ WlT,
                     const float* __restrict__ bl, const float* __restrict__ be2,
                     unsigned short* __restrict__ xpb, float* __restrict__ btp,
                     float* __restrict__ agg) {
    int wid = (blockIdx.x * blockDim.x + threadIdx.x) >> 6;
    int lane = threadIdx.x & 63;
    int s0 = wid * 4;
    if (s0 >= NN) return;
    int nv = (NN - s0 < 4) ? (NN - s0) : 4;
    float nvv[4], acc[4], bt[4];
    float blv = bl[lane];
    #pragma unroll
    for (int i = 0; i < 4; i++) {
        int s = s0 + (i < nv ? i : nv - 1);
        nvv[i] = nf[(size_t)s * DD + lane];
        acc[i] = blv;
        bt[i] = 0.f;
    }
    for (int d = 0; d < 64; d++) {
        float wv = WlT[d * 64 + lane];
        #pragma unroll
        for (int i = 0; i < 4; i++)
            acc[i] = fmaf(__shfl(nvv[i], d, 64), wv, acc[i]);
    }
    for (int d = 0; d < 64; d++) {
        float bv = be2[d * 64 + lane];
        #pragma unroll
        for (int i = 0; i < 4; i++)
            bt[i] = fmaf(__shfl(acc[i], d, 64), bv, bt[i]);
    }
    #pragma unroll
    for (int i = 0; i < 4; i++) {
        if (i < nv) {
            xpb[(size_t)(s0 + i) * DD + lane] = f2b(acc[i]);
            btp[(size_t)(s0 + i) * DD + lane] = bt[i];
            agg[(size_t)(s0 + i) * DD + lane] = 0.f;
        }
    }
}

// Fused V-GEMM + edge MFMA. Block = 16 waves (1024 thr), 16 groups. (verified R9)
__global__ __launch_bounds__(1024, 8) void k_fv(
        const unsigned short* __restrict__ xpb,
        const unsigned short* __restrict__ Apk,
        const int* __restrict__ g_src, const int* __restrict__ g_base,
        const int* __restrict__ g_cnt, const int* __restrict__ d_ng,
        const unsigned short* __restrict__ ehs, const int* __restrict__ dsts,
        const float* __restrict__ btp, float* __restrict__ agg) {
    __shared__ unsigned char lds[65536];
    int ng = *d_ng;
    int nb = blockIdx.x * 16;
    if (nb >= ng) return;
    int tid = threadIdx.x;
    int w = tid >> 6, lane = tid & 63;
    int g = lane >> 4, n = lane & 15;

    int srcn = g_src[nb + n];
    const unsigned short* xr = xpb + (size_t)srcn * DD + g * 8;
    bf16x8 xb0 = *(const bf16x8*)xr;
    bf16x8 xb1 = *(const bf16x8*)(xr + 32);

    int gi = nb + w;
    int sq = g_src[gi], bq = g_base[gi], cq = g_cnt[gi];

    f32x4 acc[4];
    #pragma unroll
    for (int nt = 0; nt < 4; nt++) {
        f32x4 z = {0.f, 0.f, 0.f, 0.f};
        acc[nt] = z;
    }

    for (int ks = 0; ks < 4; ks++) {
        if (ks) __syncthreads();
        #pragma unroll
        for (int hB = 0; hB < 2; hB++) {
            int ho = hB * 2 + (g >> 1);
            int hq0 = (g & 1) * 4;
            int abase = (n << 12) | (ho << 4) | (hq0 << 1);
            const unsigned short* apks =
                Apk + (size_t)((ks * 2 + hB) * 64 + (w << 2)) * 1024 + g * 128 + n * 8;
            #pragma unroll
            for (int fi = 0; fi < 4; fi++) {
                int f = (w << 2) + fi;
                const unsigned short* ap = apks + fi * 1024;
                bf16x8 A0 = *(const bf16x8*)ap;
                bf16x8 A1 = *(const bf16x8*)(ap + 512);
                f32x4 d = {0.f, 0.f, 0.f, 0.f};
                d = __builtin_amdgcn_mfma_f32_16x16x32_bf16(A0, xb0, d, 0, 0, 0);
                d = __builtin_amdgcn_mfma_f32_16x16x32_bf16(A1, xb1, d, 0, 0, 0);
                unsigned int lo = (unsigned)f2b(d[0]) | ((unsigned)f2b(d[1]) << 16);
                unsigned int hi = (unsigned)f2b(d[2]) | ((unsigned)f2b(d[3]) << 16);
                int addr = abase | (f << 6);
                addr ^= ((n ^ f) & 7) << 4;
                *(unsigned long long*)(lds + addr) =
                    (unsigned long long)lo | ((unsigned long long)hi << 32);
            }
        }
        bf16x8 aeh = *(const bf16x8*)(ehs + (size_t)(bq + n) * EH_ + ks * 32 + g * 8);
        __syncthreads();
        bf16x8 Bf[4];
        #pragma unroll
        for (int nt = 0; nt < 4; nt++) {
            int f = nt * 16 + n;
            int addr = (w << 12) | (f << 6) | (g << 4);
            addr ^= ((w ^ f) & 7) << 4;
            Bf[nt] = *(const bf16x8*)(lds + addr);
        }
        #pragma unroll
        for (int nt = 0; nt < 4; nt++)
            acc[nt] = __builtin_amdgcn_mfma_f32_16x16x32_bf16(aeh, Bf[nt], acc[nt], 0, 0, 0);
    }
    if (cq == 0) return;
    #pragma unroll
    for (int nt = 0; nt < 4; nt++) {
        float btv = btp[(size_t)sq * DD + nt * 16 + n];
        #pragma unroll
        for (int rg = 0; rg < 4; rg++) {
            int m = g * 4 + rg;
            if (m < cq) {
                int dn = dsts[bq + m];
                atomicAdd(&agg[(size_t)dn * DD + nt * 16 + n], acc[nt][rg] + btv);
            }
        }
    }
}

// MFMA GRU + xp + btp. Block = 4 waves, 64 nodes (4 m-tiles of 16). (verified R12)
__global__ void k_gx(const unsigned short* __restrict__ nfvb,
                     const unsigned short* __restrict__ hidb,
                     const float* __restrict__ hid,
                     const unsigned short* __restrict__ Gpk,
                     const float* __restrict__ bih, const float* __restrict__ bhh,
                     const float* __restrict__ bl,
                     float* __restrict__ out_nf, unsigned short* __restrict__ xpb,
                     float* __restrict__ btp, int doXp) {
    __shared__ unsigned short s_nf[64 * 64];
    __shared__ unsigned short s_xp[64 * 64];
    int tid = threadIdx.x;
    int w = tid >> 6, lane = tid & 63;
    int g = lane >> 4, n = lane & 15;
    int nb = blockIdx.x * 64;
    int jj = w * 16 + n;

    bf16x8 Br[4], Bz[4], Bi[2], Bh[2], Bw[2], Be[2];
    #pragma unroll
    for (int q = 0; q < 4; q++) {
        Br[q] = *(const bf16x8*)(Gpk + RZ_OFF + (size_t)(((w) * 4 + q) * 4 + g) * 128 + n * 8);
        Bz[q] = *(const bf16x8*)(Gpk + RZ_OFF + (size_t)(((w + 4) * 4 + q) * 4 + g) * 128 + n * 8);
    }
    #pragma unroll
    for (int q = 0; q < 2; q++) {
        Bi[q] = *(const bf16x8*)(Gpk + NI_OFF + (size_t)((w * 2 + q) * 4 + g) * 128 + n * 8);
        Bh[q] = *(const bf16x8*)(Gpk + NH_OFF + (size_t)((w * 2 + q) * 4 + g) * 128 + n * 8);
        Bw[q] = *(const bf16x8*)(Gpk + WL_OFF + (size_t)((w * 2 + q) * 4 + g) * 128 + n * 8);
        Be[q] = *(const bf16x8*)(Gpk + BE_OFF + (size_t)((w * 2 + q) * 4 + g) * 128 + n * 8);
    }
    float br_ = bih[jj] + bhh[jj];
    float bz_ = bih[64 + jj] + bhh[64 + jj];
    float bi_ = bih[128 + jj];
    float bh_ = bhh[128 + jj];
    float blv = bl[jj];

    #pragma unroll
    for (int mt = 0; mt < 4; mt++) {
        int arow = nb + mt * 16 + n;
        const unsigned short* na = nfvb + (size_t)arow * DD + g * 8;
        const unsigned short* ha = hidb + (size_t)arow * DD + g * 8;
        bf16x8 A0 = *(const bf16x8*)na, A1 = *(const bf16x8*)(na + 32);
        bf16x8 H0 = *(const bf16x8*)ha, H1 = *(const bf16x8*)(ha + 32);
        f32x4 aR = {0.f, 0.f, 0.f, 0.f}, aZ = aR, aI = aR, aH = aR;
        aR = __builtin_amdgcn_mfma_f32_16x16x32_bf16(A0, Br[0], aR, 0, 0, 0);
        aR = __builtin_amdgcn_mfma_f32_16x16x32_bf16(A1, Br[1], aR, 0, 0, 0);
        aR = __builtin_amdgcn_mfma_f32_16x16x32_bf16(H0, Br[2], aR, 0, 0, 0);
        aR = __builtin_amdgcn_mfma_f32_16x16x32_bf16(H1, Br[3], aR, 0, 0, 0);
        aZ = __builtin_amdgcn_mfma_f32_16x16x32_bf16(A0, Bz[0], aZ, 0, 0, 0);
        aZ = __builtin_amdgcn_mfma_f32_16x16x32_bf16(A1, Bz[1], aZ, 0, 0, 0);
        aZ = __builtin_amdgcn_mfma_f32_16x16x32_bf16(H0, Bz[2], aZ, 0, 0, 0);
        aZ = __builtin_amdgcn_mfma_f32_16x16x32_bf16(H1, Bz[3], aZ, 0, 0, 0);
        aI = __builtin_amdgcn_mfma_f32_16x16x32_bf16(A0, Bi[0], aI, 0, 0, 0);
        aI = __builtin_amdgcn_mfma_f32_16x16x32_bf16(A1, Bi[1], aI, 0, 0, 0);
        aH = __builtin_amdgcn_mfma_f32_16x16x32_bf16(H0, Bh[0], aH, 0, 0, 0);
        aH = __builtin_amdgcn_mfma_f32_16x16x32_bf16(H1, Bh[1], aH, 0, 0, 0);
        #pragma unroll
        for (int rg = 0; rg < 4; rg++) {
            int row = mt * 16 + g * 4 + rg;
            int node = nb + row;
            float r = 1.f / (1.f + __expf(-(aR[rg] + br_)));
            float z = 1.f / (1.f + __expf(-(aZ[rg] + bz_)));
            float nn2 = tanhf(aI[rg] + bi_ + r * (aH[rg] + bh_));
            float hv = (node < NN) ? hid[(size_t)node * DD + jj] : 0.f;
            float nf_ = (1.f - z) * nn2 + z * hv;
            if (node < NN) out_nf[(size_t)node * DD + jj] = nf_;
            int ba = (row * 128 + jj * 2) ^ ((row & 7) << 4);
            s_nf[ba >> 1] = f2b(nf_);
        }
    }
    if (!doXp) return;
    __syncthreads();
    #pragma unroll
    for (int mt = 0; mt < 4; mt++) {
        int row = mt * 16 + n;
        int sw = (row & 7) << 4;
        bf16x8 X0 = *(const bf16x8*)((const unsigned char*)s_nf + ((row * 128 + g * 16) ^ sw));
        bf16x8 X1 = *(const bf16x8*)((const unsigned char*)s_nf + ((row * 128 + 64 + g * 16) ^ sw));
        f32x4 aX = {0.f, 0.f, 0.f, 0.f};
        aX = __builtin_amdgcn_mfma_f32_16x16x32_bf16(X0, Bw[0], aX, 0, 0, 0);
        aX = __builtin_amdgcn_mfma_f32_16x16x32_bf16(X1, Bw[1], aX, 0, 0, 0);
        #pragma unroll
        for (int rg = 0; rg < 4; rg++) {
            int row2 = mt * 16 + g * 4 + rg;
            int ba = (row2 * 128 + jj * 2) ^ ((row2 & 7) << 4);
            s_xp[ba >> 1] = f2b(aX[rg] + blv);
        }
    }
    __syncthreads();
    {
        int row = w * 16 + n;
        int sw = (row & 7) << 4;
        #pragma unroll
        for (int h2 = 0; h2 < 2; h2++) {
            int byteo = (row * 128 + (h2 * 4 + g) * 16) ^ sw;
            bf16x8 v = *(const bf16x8*)((const unsigned char*)s_xp + byteo);
            *(bf16x8*)(xpb + (size_t)(nb + row) * DD + (h2 * 4 + g) * 8) = v;
        }
    }
    #pragma unroll
    for (int mt = 0; mt < 4; mt++) {
        int row = mt * 16 + n;
        int sw = (row & 7) << 4;
        bf16x8 X0 = *(const bf16x8*)((const unsigned char*)s_xp + ((row * 128 + g * 16) ^ sw));
        bf16x8 X1 = *(const bf16x8*)((const unsigned char*)s_xp + ((row * 128 + 64 + g * 16) ^ sw));
        f32x4 aB = {0.f, 0.f, 0.f, 0.f};
        aB = __builtin_amdgcn_mfma_f32_16x16x32_bf16(X0, Be[0], aB, 0, 0, 0);
        aB = __builtin_amdgcn_mfma_f32_16x16x32_bf16(X1, Be[1], aB, 0, 0, 0);
        #pragma unroll
        for (int rg = 0; rg < 4; rg++) {
            int node = nb + mt * 16 + g * 4 + rg;
            if (node < NN) btp[(size_t)node * DD + jj] = aB[rg];
        }
    }
}

extern "C" void kernel_launch(void* const* d_in, const int* in_sizes, int n_in,
                              void* d_out, int out_size, void* d_ws, size_t ws_size,
                              hipStream_t stream) {
    const float* x   = (const float*)d_in[0];
    const int*   ei  = (const int*)d_in[1];
    const float* ea  = (const float*)d_in[2];
    const float* Wp  = (const float*)d_in[3];
    const float* bp  = (const float*)d_in[4];
    const float* W1  = (const float*)d_in[5];
    const float* b1  = (const float*)d_in[6];
    const float* W2  = (const float*)d_in[7];
    const float* b2  = (const float*)d_in[8];
    const float* Wl  = (const float*)d_in[9];
    const float* bl  = (const float*)d_in[10];
    const float* Wih = (const float*)d_in[11];
    const float* Whh = (const float*)d_in[12];
    const float* bih = (const float*)d_in[13];
    const float* bhh = (const float*)d_in[14];
    const int* srcv = ei;
    const int* dstv = ei + NE;

    float* p = (float*)d_ws;
    size_t off = 0;
    auto alloc = [&](size_t n) { n = (n + 3) & ~(size_t)3; float* q = p + off; off += n; return q; };
    float* nf   = alloc((size_t)NN * DD);
    float* hid  = alloc((size_t)NN * DD);
    float* btp  = alloc((size_t)NN * DD);
    float* agg  = alloc((size_t)NN * DD);
    float* cnt  = alloc(NN);
    unsigned short* ehs = (unsigned short*)alloc((size_t)(NE + 16) * EH_ / 2);  // bf16
    float* WlT  = alloc(64 * 64);
    int* hist   = (int*)alloc(NN);
    int* rowptr = (int*)alloc(NN + 1);
    int* cursor = (int*)alloc(NN);
    int* perm   = (int*)alloc(NE);
    int* dsts_s = (int*)alloc(NE);
    int* g_src  = (int*)alloc(GCAP);   // g_src/g_base/g_cnt contiguous
    int* g_base = (int*)alloc(GCAP);
    int* g_cnt  = (int*)alloc(GCAP);
    int* d_ng   = (int*)alloc(4);
    unsigned short* Apk  = (unsigned short*)alloc((size_t)(1 << 19) / 2);      // bf16, 1MB
    unsigned short* Gpk  = (unsigned short*)alloc((size_t)G_TOT / 2);          // bf16, 64KB
    unsigned short* xpb  = (unsigned short*)alloc((size_t)PADN * DD / 2);      // bf16
    unsigned short* nfvb = (unsigned short*)alloc((size_t)PADN * DD / 2);      // bf16
    unsigned short* hidb = (unsigned short*)alloc((size_t)PADN * DD / 2);      // bf16

    // ---- one-time preprocessing ----
    k_zero2<<<(NN + 255) / 256, 256, 0, stream>>>(cnt, (float*)hist, NN);
    k_zero<<<(3 * GCAP + 255) / 256, 256, 0, stream>>>((float*)g_src, 3 * GCAP);
    k_proj<<<(PADN + 3) / 4, 256, 0, stream>>>(x, Wp, bp, nf, hid, hidb);
    k_pA<<<(1 << 19) / 256, 256, 0, stream>>>(W2, Apk);
    k_pG<<<(G_TOT + 255) / 256, 256, 0, stream>>>(Wih, Whh, Wl, b2, Gpk);
    k_tr64<<<16, 256, 0, stream>>>(Wl, WlT);
    k_degs<<<(NE + 255) / 256, 256, 0, stream>>>(srcv, dstv, hist, cnt);
    k_scangrp<<<1, 1024, 0, stream>>>(hist, rowptr, cursor, g_src, g_base, g_cnt, d_ng);
    k_scatter<<<(NE + 255) / 256, 256, 0, stream>>>(srcv, dstv, cursor, perm, dsts_s);
    k_eh_s<<<(NE + EPB - 1) / EPB, 256, 0, stream>>>(ea, W1, b1, perm, ehs);

    const int nw_quarter = (NN + 3) / 4;
    const int gx_blocks = (NN + 63) / 64;
    k_xp<<<(nw_quarter + 3) / 4, 256, 0, stream>>>(nf, WlT, bl, b2, xpb, btp, agg);
    for (int s = 0; s < NSTEPS; s++) {
        k_fv<<<GCAP / 16, 1024, 0, stream>>>(xpb, Apk, g_src, g_base, g_cnt, d_ng,
                                             ehs, dsts_s, btp, agg);
        k_prep<<<(PADN * DD + 255) / 256, 256, 0, stream>>>(agg, cnt, nfvb, agg);
        float* dest = (s == NSTEPS - 1) ? (float*)d_out : nf;
        k_gx<<<gx_blocks, 256, 0, stream>>>(nfvb, hidb, hid, Gpk, bih, bhh, bl,
                                            dest, xpb, btp,
                                            (s < NSTEPS - 1) ? 1 : 0);
    }
}